// Round 2
// baseline (1191.223 us; speedup 1.0000x reference)
//
#include <hip/hip_runtime.h>
#include <math.h>

// Problem constants (from reference)
#define Bb    2
#define Ss    1024
#define HIDd  2048
#define NHh   16
#define HDd   128
#define SBc   20      // floor(0.02*1024+0.5)
#define SELBc 61      // floor(0.06*1024+0.5)
#define RBc   82      // floor(0.08*1024+0.5)
#define CBc   163     // SB+SELB+RB
#define FFf   0.9f
#define MASKVAL (-3.4028234663852886e38f)
#define NBH   (Bb*NHh)       // 32
#define NROWS (NBH*Ss)       // 32768

typedef __attribute__((ext_vector_type(8))) short short8;
typedef __attribute__((ext_vector_type(4))) float f32x4;

__device__ __forceinline__ unsigned short f2b(float f) {
    unsigned u = __float_as_uint(f);
    u = (u + 0x7FFFu + ((u >> 16) & 1u)) >> 16;   // RNE
    return (unsigned short)u;
}
__device__ __forceinline__ float b2f(unsigned short h) {
    return __uint_as_float((unsigned)h << 16);
}

// ---------------------------------------------------------------------------
// Async global->LDS direct DMA (16B/lane). LDS dest = wave-uniform base +
// lane*16 (hardware rule); all call sites below have tid-linear LDS layouts.
// ---------------------------------------------------------------------------
#if defined(__has_builtin)
#if __has_builtin(__builtin_amdgcn_global_load_lds)
#define USE_GLD 1
#endif
#endif

__device__ __forceinline__ void gload16(const void* g, void* l) {
#ifdef USE_GLD
    __builtin_amdgcn_global_load_lds(
        (const __attribute__((address_space(1))) void*)g,
        (__attribute__((address_space(3))) void*)l, 16, 0, 0);
#else
    *(short8*)l = *(const short8*)g;
#endif
}

// ---------------------------------------------------------------------------
// fp32 -> split bf16 (hi + lo). lo = bf16(x - fp32(hi)).
// ---------------------------------------------------------------------------
__global__ __launch_bounds__(256) void conv_split(const float* __restrict__ x,
                                                  unsigned short* __restrict__ yh,
                                                  unsigned short* __restrict__ yl, int n4)
{
    int i = blockIdx.x * 256 + threadIdx.x;
    if (i >= n4) return;
    float4 v = ((const float4*)x)[i];
    ushort4 h, l;
    h.x = f2b(v.x); l.x = f2b(v.x - b2f(h.x));
    h.y = f2b(v.y); l.y = f2b(v.y - b2f(h.y));
    h.z = f2b(v.z); l.z = f2b(v.z - b2f(h.z));
    h.w = f2b(v.w); l.w = f2b(v.w - b2f(h.w));
    ((ushort4*)yh)[i] = h;
    ((ushort4*)yl)[i] = l;
}

// ---------------------------------------------------------------------------
// Transpose + convert: W[k][n] fp32 -> Wt[n][k] bf16 (single).
// ---------------------------------------------------------------------------
__global__ __launch_bounds__(256) void tconv(const float* __restrict__ W,
                                             unsigned short* __restrict__ Wt,
                                             int Kdim, int Ndim)
{
    __shared__ float T[64][65];
    int n0 = blockIdx.x * 64, k0 = blockIdx.y * 64;
    int tid = threadIdx.x;
    int rr = tid >> 4, cc = (tid & 15) * 4;
#pragma unroll
    for (int p = 0; p < 4; ++p) {
        int r = rr + p * 16;
        float4 x = *(const float4*)&W[(size_t)(k0 + r) * Ndim + n0 + cc];
        T[r][cc] = x.x; T[r][cc + 1] = x.y; T[r][cc + 2] = x.z; T[r][cc + 3] = x.w;
    }
    __syncthreads();
#pragma unroll
    for (int p = 0; p < 4; ++p) {
        int rn = rr + p * 16;
        ushort4 o;
        o.x = f2b(T[cc][rn]);     o.y = f2b(T[cc + 1][rn]);
        o.z = f2b(T[cc + 2][rn]); o.w = f2b(T[cc + 3][rn]);
        *(ushort4*)&Wt[(size_t)(n0 + rn) * Kdim + k0 + cc] = o;
    }
}

// ---------------------------------------------------------------------------
// Transpose + split convert: W[k][n] fp32 -> Wth/Wtl[n][k] bf16 hi/lo.
// ---------------------------------------------------------------------------
__global__ __launch_bounds__(256) void tconv_split(const float* __restrict__ W,
                                                   unsigned short* __restrict__ Wth,
                                                   unsigned short* __restrict__ Wtl,
                                                   int Kdim, int Ndim)
{
    __shared__ float T[64][65];
    int n0 = blockIdx.x * 64, k0 = blockIdx.y * 64;
    int tid = threadIdx.x;
    int rr = tid >> 4, cc = (tid & 15) * 4;
#pragma unroll
    for (int p = 0; p < 4; ++p) {
        int r = rr + p * 16;
        float4 x = *(const float4*)&W[(size_t)(k0 + r) * Ndim + n0 + cc];
        T[r][cc] = x.x; T[r][cc + 1] = x.y; T[r][cc + 2] = x.z; T[r][cc + 3] = x.w;
    }
    __syncthreads();
#pragma unroll
    for (int p = 0; p < 4; ++p) {
        int rn = rr + p * 16;
        float v0 = T[cc][rn], v1 = T[cc + 1][rn], v2 = T[cc + 2][rn], v3 = T[cc + 3][rn];
        ushort4 h, l;
        h.x = f2b(v0); l.x = f2b(v0 - b2f(h.x));
        h.y = f2b(v1); l.y = f2b(v1 - b2f(h.y));
        h.z = f2b(v2); l.z = f2b(v2 - b2f(h.z));
        h.w = f2b(v3); l.w = f2b(v3 - b2f(h.w));
        *(ushort4*)&Wth[(size_t)(n0 + rn) * Kdim + k0 + cc] = h;
        *(ushort4*)&Wtl[(size_t)(n0 + rn) * Kdim + k0 + cc] = l;
    }
}

// ---------------------------------------------------------------------------
// Single-bf16 MFMA GEMM: C = A @ Bt^T. 128x128 tile, 4 waves, 4x4 frags.
// Staging via global_load_lds (LDS layout is tid-linear *16B).
// MODE 0: C[m*N+n].  MODE 1: qkv permute -> C[((b*NH+h)*S+s)*HD+d].
// ---------------------------------------------------------------------------
template<int MODE>
__global__ __launch_bounds__(256) void gemm_bf16t(const unsigned short* __restrict__ A,
                                                  const unsigned short* __restrict__ Bt,
                                                  float* __restrict__ C,
                                                  int M, int N, int K)
{
    __shared__ unsigned short As[128 * 32];
    __shared__ unsigned short Bs[128 * 32];
    const int tid = threadIdx.x;
    const int bm = blockIdx.y * 128, bn = blockIdx.x * 128;
    const int lane = tid & 63, wid = tid >> 6;
    const int wr = (wid >> 1) * 64, wc = (wid & 1) * 64;
    const int lm = lane & 15, lk = (lane >> 4) * 8;

    f32x4 acc[4][4];
#pragma unroll
    for (int mi = 0; mi < 4; ++mi)
#pragma unroll
        for (int ni = 0; ni < 4; ++ni) acc[mi][ni] = 0.0f;

    for (int k0 = 0; k0 < K; k0 += 32) {
#pragma unroll
        for (int l = 0; l < 2; ++l) {
            int L = tid + l * 256;
            int row = L >> 2, c8 = (L & 3) * 8;
            gload16(&A[(size_t)(bm + row) * K + k0 + c8], &As[L * 8]);
            gload16(&Bt[(size_t)(bn + row) * K + k0 + c8], &Bs[L * 8]);
        }
        __syncthreads();
        short8 af[4], bf[4];
#pragma unroll
        for (int mi = 0; mi < 4; ++mi) af[mi] = *(short8*)&As[(wr + mi * 16 + lm) * 32 + lk];
#pragma unroll
        for (int ni = 0; ni < 4; ++ni) bf[ni] = *(short8*)&Bs[(wc + ni * 16 + lm) * 32 + lk];
#pragma unroll
        for (int mi = 0; mi < 4; ++mi)
#pragma unroll
            for (int ni = 0; ni < 4; ++ni)
                acc[mi][ni] = __builtin_amdgcn_mfma_f32_16x16x32_bf16(af[mi], bf[ni], acc[mi][ni], 0, 0, 0);
        __syncthreads();
    }
    const int lr = (lane >> 4) * 4;  // C/D: col=lane&15, row=(lane>>4)*4+reg
#pragma unroll
    for (int mi = 0; mi < 4; ++mi)
#pragma unroll
        for (int ni = 0; ni < 4; ++ni)
#pragma unroll
            for (int r = 0; r < 4; ++r) {
                int m = bm + wr + mi * 16 + lr + r;
                int n = bn + wc + ni * 16 + lm;
                float vv = acc[mi][ni][r];
                if (MODE == 0) {
                    C[(size_t)m * N + n] = vv;
                } else {
                    int b_ = m / Ss, s_ = m % Ss;
                    int h_ = n / HDd, d_ = n % HDd;
                    C[(size_t)((b_ * NHh + h_) * Ss + s_) * HDd + d_] = vv;
                }
            }
}

// ---------------------------------------------------------------------------
// Split-bf16 MFMA GEMM (hi/lo): C = (Ah+Al) @ (Bh+Bl)^T, dropping Al*Bl.
// 3 MFMAs per fragment pair. Staging via global_load_lds.
// ---------------------------------------------------------------------------
template<int MODE>
__global__ __launch_bounds__(256) void gemm_split(const unsigned short* __restrict__ Ah,
                                                  const unsigned short* __restrict__ Al,
                                                  const unsigned short* __restrict__ Bh,
                                                  const unsigned short* __restrict__ Bl,
                                                  float* __restrict__ C,
                                                  int M, int N, int K)
{
    __shared__ unsigned short AsH[128 * 32], AsL[128 * 32];
    __shared__ unsigned short BsH[128 * 32], BsL[128 * 32];
    const int tid = threadIdx.x;
    const int bm = blockIdx.y * 128, bn = blockIdx.x * 128;
    const int lane = tid & 63, wid = tid >> 6;
    const int wr = (wid >> 1) * 64, wc = (wid & 1) * 64;
    const int lm = lane & 15, lk = (lane >> 4) * 8;

    f32x4 acc[4][4];
#pragma unroll
    for (int mi = 0; mi < 4; ++mi)
#pragma unroll
        for (int ni = 0; ni < 4; ++ni) acc[mi][ni] = 0.0f;

    for (int k0 = 0; k0 < K; k0 += 32) {
#pragma unroll
        for (int l = 0; l < 2; ++l) {
            int L = tid + l * 256;
            int row = L >> 2, c8 = (L & 3) * 8;
            size_t ga = (size_t)(bm + row) * K + k0 + c8;
            size_t gb = (size_t)(bn + row) * K + k0 + c8;
            gload16(&Ah[ga], &AsH[L * 8]);
            gload16(&Al[ga], &AsL[L * 8]);
            gload16(&Bh[gb], &BsH[L * 8]);
            gload16(&Bl[gb], &BsL[L * 8]);
        }
        __syncthreads();
        short8 ah[4], al[4], bh[4], bl[4];
#pragma unroll
        for (int mi = 0; mi < 4; ++mi) {
            ah[mi] = *(short8*)&AsH[(wr + mi * 16 + lm) * 32 + lk];
            al[mi] = *(short8*)&AsL[(wr + mi * 16 + lm) * 32 + lk];
        }
#pragma unroll
        for (int ni = 0; ni < 4; ++ni) {
            bh[ni] = *(short8*)&BsH[(wc + ni * 16 + lm) * 32 + lk];
            bl[ni] = *(short8*)&BsL[(wc + ni * 16 + lm) * 32 + lk];
        }
#pragma unroll
        for (int mi = 0; mi < 4; ++mi)
#pragma unroll
            for (int ni = 0; ni < 4; ++ni) {
                acc[mi][ni] = __builtin_amdgcn_mfma_f32_16x16x32_bf16(ah[mi], bh[ni], acc[mi][ni], 0, 0, 0);
                acc[mi][ni] = __builtin_amdgcn_mfma_f32_16x16x32_bf16(ah[mi], bl[ni], acc[mi][ni], 0, 0, 0);
                acc[mi][ni] = __builtin_amdgcn_mfma_f32_16x16x32_bf16(al[mi], bh[ni], acc[mi][ni], 0, 0, 0);
            }
        __syncthreads();
    }
    const int lr = (lane >> 4) * 4;
#pragma unroll
    for (int mi = 0; mi < 4; ++mi)
#pragma unroll
        for (int ni = 0; ni < 4; ++ni)
#pragma unroll
            for (int r = 0; r < 4; ++r) {
                int m = bm + wr + mi * 16 + lr + r;
                int n = bn + wc + ni * 16 + lm;
                float vv = acc[mi][ni][r];
                if (MODE == 0) {
                    C[(size_t)m * N + n] = vv;
                } else {
                    int b_ = m / Ss, s_ = m % Ss;
                    int h_ = n / HDd, d_ = n % HDd;
                    C[(size_t)((b_ * NHh + h_) * Ss + s_) * HDd + d_] = vv;
                }
            }
}

// ---------------------------------------------------------------------------
// RoPE (fp32 math) -> split bf16 q,k (hi/lo).
// ---------------------------------------------------------------------------
__global__ __launch_bounds__(64) void rope_qk_split(const float* __restrict__ q,
                                                    const float* __restrict__ k,
                                                    unsigned short* __restrict__ qh,
                                                    unsigned short* __restrict__ ql,
                                                    unsigned short* __restrict__ kh,
                                                    unsigned short* __restrict__ kl)
{
    int idx = blockIdx.x;          // bh*S + s
    int s = idx % Ss;
    int d = threadIdx.x;           // 0..63
    float inv = powf(10000.0f, -2.0f * (float)d / 128.0f);
    float fr = (float)s * inv;
    float c = cosf(fr), sn = sinf(fr);
    size_t base = (size_t)idx * HDd;
    float q1 = q[base + d], q2 = q[base + d + 64];
    float k1 = k[base + d], k2 = k[base + d + 64];
    float qa = q1 * c - q2 * sn, qbv = q2 * c + q1 * sn;
    float ka = k1 * c - k2 * sn, kbv = k2 * c + k1 * sn;
    unsigned short h;
    h = f2b(qa);  qh[base + d]      = h; ql[base + d]      = f2b(qa  - b2f(h));
    h = f2b(qbv); qh[base + d + 64] = h; ql[base + d + 64] = f2b(qbv - b2f(h));
    h = f2b(ka);  kh[base + d]      = h; kl[base + d]      = f2b(ka  - b2f(h));
    h = f2b(kbv); kh[base + d + 64] = h; kl[base + d + 64] = f2b(kbv - b2f(h));
}

// ---------------------------------------------------------------------------
// attn = q k^T / sqrt(HD) via split-bf16 MFMA, causal mask to MASKVAL.
// ---------------------------------------------------------------------------
__global__ __launch_bounds__(256) void attn_qk_split(const unsigned short* __restrict__ qh,
                                                     const unsigned short* __restrict__ ql,
                                                     const unsigned short* __restrict__ kh,
                                                     const unsigned short* __restrict__ kl,
                                                     float* __restrict__ attn)
{
    const int bh = blockIdx.z;
    const int bm = blockIdx.y * 128, bn = blockIdx.x * 128;
    float* C = attn + (size_t)bh * Ss * Ss;
    const int tid = threadIdx.x;

    if (blockIdx.x > blockIdx.y) {  // fully above diagonal
        float4 mv = make_float4(MASKVAL, MASKVAL, MASKVAL, MASKVAL);
#pragma unroll
        for (int i = 0; i < 16; ++i) {
            int L = tid + i * 256;
            int row = L >> 5, c4 = (L & 31) * 4;
            *(float4*)&C[(size_t)(bm + row) * Ss + bn + c4] = mv;
        }
        return;
    }
    const size_t hb = (size_t)bh * Ss * HDd;
    const unsigned short* Ah = qh + hb;
    const unsigned short* Al = ql + hb;
    const unsigned short* Bh = kh + hb;
    const unsigned short* Bl = kl + hb;

    __shared__ unsigned short AsH[128 * 32], AsL[128 * 32];
    __shared__ unsigned short BsH[128 * 32], BsL[128 * 32];
    const int lane = tid & 63, wid = tid >> 6;
    const int wr = (wid >> 1) * 64, wc = (wid & 1) * 64;
    const int lm = lane & 15, lk = (lane >> 4) * 8;

    f32x4 acc[4][4];
#pragma unroll
    for (int mi = 0; mi < 4; ++mi)
#pragma unroll
        for (int ni = 0; ni < 4; ++ni) acc[mi][ni] = 0.0f;

    for (int k0 = 0; k0 < HDd; k0 += 32) {
#pragma unroll
        for (int l = 0; l < 2; ++l) {
            int L = tid + l * 256;
            int row = L >> 2, c8 = (L & 3) * 8;
            size_t ga = (size_t)(bm + row) * HDd + k0 + c8;
            size_t gb = (size_t)(bn + row) * HDd + k0 + c8;
            gload16(&Ah[ga], &AsH[L * 8]);
            gload16(&Al[ga], &AsL[L * 8]);
            gload16(&Bh[gb], &BsH[L * 8]);
            gload16(&Bl[gb], &BsL[L * 8]);
        }
        __syncthreads();
        short8 ah[4], al[4], bh2[4], bl2[4];
#pragma unroll
        for (int mi = 0; mi < 4; ++mi) {
            ah[mi] = *(short8*)&AsH[(wr + mi * 16 + lm) * 32 + lk];
            al[mi] = *(short8*)&AsL[(wr + mi * 16 + lm) * 32 + lk];
        }
#pragma unroll
        for (int ni = 0; ni < 4; ++ni) {
            bh2[ni] = *(short8*)&BsH[(wc + ni * 16 + lm) * 32 + lk];
            bl2[ni] = *(short8*)&BsL[(wc + ni * 16 + lm) * 32 + lk];
        }
#pragma unroll
        for (int mi = 0; mi < 4; ++mi)
#pragma unroll
            for (int ni = 0; ni < 4; ++ni) {
                acc[mi][ni] = __builtin_amdgcn_mfma_f32_16x16x32_bf16(ah[mi], bh2[ni], acc[mi][ni], 0, 0, 0);
                acc[mi][ni] = __builtin_amdgcn_mfma_f32_16x16x32_bf16(ah[mi], bl2[ni], acc[mi][ni], 0, 0, 0);
                acc[mi][ni] = __builtin_amdgcn_mfma_f32_16x16x32_bf16(al[mi], bh2[ni], acc[mi][ni], 0, 0, 0);
            }
        __syncthreads();
    }
    const float scale = 0.08838834764831845f;  // 1/sqrt(128)
    const int lr = (lane >> 4) * 4;
#pragma unroll
    for (int mi = 0; mi < 4; ++mi)
#pragma unroll
        for (int ni = 0; ni < 4; ++ni)
#pragma unroll
            for (int r = 0; r < 4; ++r) {
                int sq = bm + wr + mi * 16 + lr + r;
                int sk = bn + wc + ni * 16 + lm;
                C[(size_t)sq * Ss + sk] = (sk <= sq) ? acc[mi][ni][r] * scale : MASKVAL;
            }
}

// ---------------------------------------------------------------------------
// Row softmax IN PLACE: attn -> scores = exp(a - rowmax) / rowsum.
// ---------------------------------------------------------------------------
__global__ __launch_bounds__(256) void softmax_rows(float* __restrict__ attn)
{
    int row = blockIdx.x;
    float4* a4 = (float4*)(attn + (size_t)row * Ss);
    int tid = threadIdx.x;
    float4 x = a4[tid];
    float m = fmaxf(fmaxf(x.x, x.y), fmaxf(x.z, x.w));
#pragma unroll
    for (int off = 32; off; off >>= 1) m = fmaxf(m, __shfl_xor(m, off));
    __shared__ float red[4];
    if ((tid & 63) == 0) red[tid >> 6] = m;
    __syncthreads();
    float mm = fmaxf(fmaxf(red[0], red[1]), fmaxf(red[2], red[3]));
    float e0 = expf(x.x - mm), e1 = expf(x.y - mm);
    float e2 = expf(x.z - mm), e3 = expf(x.w - mm);
    float s = e0 + e1 + e2 + e3;
#pragma unroll
    for (int off = 32; off; off >>= 1) s += __shfl_xor(s, off);
    __shared__ float red2[4];
    if ((tid & 63) == 0) red2[tid >> 6] = s;
    __syncthreads();
    float inv = 1.0f / (red2[0] + red2[1] + red2[2] + red2[3]);
    a4[tid] = make_float4(e0 * inv, e1 * inv, e2 * inv, e3 * inv);
}

// ---------------------------------------------------------------------------
// DPP cross-lane helpers (VALU-latency, no LDS pipe).
// ---------------------------------------------------------------------------
template<int CTRL>
__device__ __forceinline__ int dpp_i(int x) {
    return __builtin_amdgcn_update_dpp(0, x, CTRL, 0xF, 0xF, true);
}
__device__ __forceinline__ float wave_sum64(float x) {
    x += __int_as_float(dpp_i<0xB1>(__float_as_int(x)));
    x += __int_as_float(dpp_i<0x4E>(__float_as_int(x)));
    x += __int_as_float(dpp_i<0x141>(__float_as_int(x)));
    x += __int_as_float(dpp_i<0x140>(__float_as_int(x)));
    int xi = __float_as_int(x);
    float a = __int_as_float(__builtin_amdgcn_readlane(xi, 0));
    float b = __int_as_float(__builtin_amdgcn_readlane(xi, 16));
    float c = __int_as_float(__builtin_amdgcn_readlane(xi, 32));
    float d = __int_as_float(__builtin_amdgcn_readlane(xi, 48));
    return (a + c) + (b + d);
}

// 64-bit packed-key (value<<32 | index) helpers: lexicographic min == exact
// float-min with first-index tie-break (values are non-negative floats).
__device__ __forceinline__ unsigned long long u64min(unsigned long long a, unsigned long long b) {
    return a < b ? a : b;
}
template<int CTRL>
__device__ __forceinline__ unsigned long long dpp64(unsigned long long x) {
    int lo = (int)(unsigned)x;
    int hi = (int)(unsigned)(x >> 32);
    unsigned l2 = (unsigned)dpp_i<CTRL>(lo);
    unsigned h2 = (unsigned)dpp_i<CTRL>(hi);
    return ((unsigned long long)h2 << 32) | (unsigned long long)l2;
}
__device__ __forceinline__ unsigned long long wave_min64k(unsigned long long x) {
    x = u64min(x, dpp64<0xB1>(x));
    x = u64min(x, dpp64<0x4E>(x));
    x = u64min(x, dpp64<0x141>(x));
    x = u64min(x, dpp64<0x140>(x));
    int lo = (int)(unsigned)x;
    int hi = (int)(unsigned)(x >> 32);
    unsigned long long a = ((unsigned long long)(unsigned)__builtin_amdgcn_readlane(hi, 0)  << 32) |
                           (unsigned long long)(unsigned)__builtin_amdgcn_readlane(lo, 0);
    unsigned long long b = ((unsigned long long)(unsigned)__builtin_amdgcn_readlane(hi, 16) << 32) |
                           (unsigned long long)(unsigned)__builtin_amdgcn_readlane(lo, 16);
    unsigned long long c = ((unsigned long long)(unsigned)__builtin_amdgcn_readlane(hi, 32) << 32) |
                           (unsigned long long)(unsigned)__builtin_amdgcn_readlane(lo, 32);
    unsigned long long d = ((unsigned long long)(unsigned)__builtin_amdgcn_readlane(hi, 48) << 32) |
                           (unsigned long long)(unsigned)__builtin_amdgcn_readlane(lo, 48);
    return u64min(u64min(a, b), u64min(c, d));
}

__device__ __forceinline__ float f4c(float4 v, int i) {
    return i == 0 ? v.x : (i == 1 ? v.y : (i == 2 ? v.z : v.w));
}

// ---------------------------------------------------------------------------
// A2S sequential scan v6.
//  v5 + :
//  - lead-chunk window hoisting: lead = local>>8 (uniform). Chunks < lead
//    are fully inside the window -> key = raw sel bits (no per-elem cmp;
//    chunk0 applies the precomputed ge mask). Chunk == lead does per-elem
//    compares. Chunks > lead contribute no keys (bit-identical: their keys
//    were all INF). All values/decisions identical to v5.
//  - scalarized evict: besti is wave-uniform -> readfirstlane + uniform
//    (chunk,slot) branches (SALU) + ONE v_cmp for the lane match, instead
//    of 16x(v_cmp + 2 cndmask).
// ---------------------------------------------------------------------------
template<int NC, int NCL>
__device__ __forceinline__ void scan_step(int t, int lane,
                                          const float4* __restrict__ A4,
                                          unsigned char* __restrict__ KP,
                                          float4 (&rb)[4],
                                          float (&sel)[4][4],
                                          float (&mf)[4][4],
                                          const int (&sreg)[4][4],
                                          bool ge)
{
    const float INFv = __int_as_float(0x7f800000);
    // snapshot row t
    float4 a[NC];
#pragma unroll
    for (int jj = 0; jj < NC; ++jj) a[jj] = rb[jj];
    // prefetch row t+4 (clamped), NCL chunks (one lookahead chunk past NC)
    int tp = t + 4; if (tp > Ss - 1) tp = Ss - 1;
#pragma unroll
    for (int jj = 0; jj < NCL; ++jj) rb[jj] = A4[tp * 256 + jj * 64 + lane];

    // masked row sum — identical add order to v4/v5 (skipped chunks add 0.0)
    float lsum = 0.0f;
#pragma unroll
    for (int jj = 0; jj < NC; ++jj) {
        float c0 = a[jj].x * mf[jj][0], c1 = a[jj].y * mf[jj][1];
        float c2 = a[jj].z * mf[jj][2], c3 = a[jj].w * mf[jj][3];
        lsum += (c0 + c1) + (c2 + c3);
    }
    float tot = wave_sum64(lsum);
    float inv = 1.0f / tot;

    const int local = t - RBc;
    const int lead = local >> 8;   // uniform: chunk containing window top

    // sel update + windowed argmin via packed (value,index) keys
    unsigned long long kmin = 0xFFFFFFFFFFFFFFFFull;
#pragma unroll
    for (int jj = 0; jj < NC; ++jj) {
        float sv[4];
#pragma unroll
        for (int i = 0; i < 4; ++i) {
            sv[i] = fmaf(FFf, sel[jj][i], f4c(a[jj], i) * inv);
            sel[jj][i] = sv[i];
        }
        if (jj < lead) {
            // fully inside window (all s <= lead*256-1 <= local)
            unsigned long long kk[4];
#pragma unroll
            for (int i = 0; i < 4; ++i) {
                unsigned hi = __float_as_uint(sv[i]);
                if (jj == 0) hi = ge ? hi : 0x7f800000u;
                kk[i] = ((unsigned long long)hi << 32) | (unsigned long long)(unsigned)sreg[jj][i];
            }
            kmin = u64min(kmin, u64min(u64min(kk[0], kk[1]), u64min(kk[2], kk[3])));
        } else if (jj == lead) {
            // partial chunk: per-element window compare
            unsigned long long kk[4];
#pragma unroll
            for (int i = 0; i < 4; ++i) {
                bool win = (sreg[jj][i] <= local) && (jj > 0 || ge);
                unsigned hi = win ? __float_as_uint(sv[i]) : 0x7f800000u;
                kk[i] = ((unsigned long long)hi << 32) | (unsigned long long)(unsigned)sreg[jj][i];
            }
            kmin = u64min(kmin, u64min(u64min(kk[0], kk[1]), u64min(kk[2], kk[3])));
        }
        // jj > lead: all out of window -> keys were all INF -> skip entirely
    }
    kmin = wave_min64k(kmin);

    // scalarized evict: besti wave-uniform
    const int besti  = __builtin_amdgcn_readfirstlane((int)(unsigned)(kmin & 0xFFFFFFFFull));
    const int echunk = besti >> 8;
    const int eslot  = besti & 3;
    const int elane  = (besti >> 2) & 63;
    const bool lmatch = (lane == elane);   // one v_cmp -> vcc
#pragma unroll
    for (int jj = 0; jj < NC; ++jj) {
        if (jj == echunk) {
#pragma unroll
            for (int i = 0; i < 4; ++i) {
                if (i == eslot) {
                    sel[jj][i] = lmatch ? INFv : sel[jj][i];
                    mf[jj][i]  = lmatch ? 0.0f : mf[jj][i];
                }
            }
        }
    }

    // keep row t+1 (chunks 0..NC-1; scores are exactly 0 above, don't-care)
    uchar4* kp4 = (uchar4*)(KP + (size_t)(t + 1) * Ss);
#pragma unroll
    for (int jj = 0; jj < NC; ++jj) {
        uchar4 kb;
        kb.x = (unsigned char)mf[jj][0];
        kb.y = (unsigned char)mf[jj][1];
        kb.z = (unsigned char)mf[jj][2];
        kb.w = (unsigned char)mf[jj][3];
        kp4[jj * 64 + lane] = kb;
    }
}

__global__ __launch_bounds__(64) void scan_kernel6(const float* __restrict__ scores,
                                                   unsigned char* __restrict__ keep)
{
    int bh = blockIdx.x;
    int lane = threadIdx.x;
    const float4* A4 = (const float4*)(scores + (size_t)bh * Ss * Ss);
    unsigned char* KP = keep + (size_t)bh * Ss * Ss;

    float sel[4][4];
    float mf[4][4];
    int sreg[4][4];
#pragma unroll
    for (int jj = 0; jj < 4; ++jj)
#pragma unroll
        for (int i = 0; i < 4; ++i) {
            sel[jj][i] = 0.0f; mf[jj][i] = 1.0f;
            sreg[jj][i] = jj * 256 + lane * 4 + i;
        }
    const bool ge = (lane * 4 >= SBc);

    // ---- warmup rows 0..162: chunk 0 only (rows <163 are zero beyond col 162) ----
    float4 w0 = A4[0 * 256 + lane];
    float4 w1 = A4[1 * 256 + lane];
    float4 w2 = A4[2 * 256 + lane];
    float4 w3 = A4[3 * 256 + lane];
#define WSTEP(W, NEXT)                                                       \
    do {                                                                     \
        float4 _a = W;                                                       \
        W = A4[(NEXT) * 256 + lane];                                         \
        sel[0][0] = fmaf(FFf, sel[0][0], _a.x);                              \
        sel[0][1] = fmaf(FFf, sel[0][1], _a.y);                              \
        sel[0][2] = fmaf(FFf, sel[0][2], _a.z);                              \
        sel[0][3] = fmaf(FFf, sel[0][3], _a.w);                              \
    } while (0)
    for (int r = 0; r < 160; r += 4) {
        WSTEP(w0, r + 4); WSTEP(w1, r + 5); WSTEP(w2, r + 6); WSTEP(w3, r + 7);
    }
#undef WSTEP
    {   // rows 160..162 tail (w3 = row 163 discarded)
        float4 tl[3] = { w0, w1, w2 };
#pragma unroll
        for (int u = 0; u < 3; ++u) {
            sel[0][0] = fmaf(FFf, sel[0][0], tl[u].x);
            sel[0][1] = fmaf(FFf, sel[0][1], tl[u].y);
            sel[0][2] = fmaf(FFf, sel[0][2], tl[u].z);
            sel[0][3] = fmaf(FFf, sel[0][3], tl[u].w);
        }
    }

    // ---- init scan prefetch: rows 163..166, chunk 0 ----
    float4 rb[4][4];
#pragma unroll
    for (int slot = 0; slot < 4; ++slot)
        rb[slot][0] = A4[(163 + slot) * 256 + lane];

    // ---- phased scan: t = 163..1022 (keep rows 164..1023) ----
    for (int t0 = 163; t0 < 255; t0 += 4) {           // 92 steps, NC=1
        scan_step<1, 2>(t0 + 0, lane, A4, KP, rb[0], sel, mf, sreg, ge);
        scan_step<1, 2>(t0 + 1, lane, A4, KP, rb[1], sel, mf, sreg, ge);
        scan_step<1, 2>(t0 + 2, lane, A4, KP, rb[2], sel, mf, sreg, ge);
        scan_step<1, 2>(t0 + 3, lane, A4, KP, rb[3], sel, mf, sreg, ge);
    }
    for (int t0 = 255; t0 < 511; t0 += 4) {           // 256 steps, NC=2
        scan_step<2, 3>(t0 + 0, lane, A4, KP, rb[0], sel, mf, sreg, ge);
        scan_step<2, 3>(t0 + 1, lane, A4, KP, rb[1], sel, mf, sreg, ge);
        scan_step<2, 3>(t0 + 2, lane, A4, KP, rb[2], sel, mf, sreg, ge);
        scan_step<2, 3>(t0 + 3, lane, A4, KP, rb[3], sel, mf, sreg, ge);
    }
    for (int t0 = 511; t0 < 767; t0 += 4) {           // 256 steps, NC=3
        scan_step<3, 4>(t0 + 0, lane, A4, KP, rb[0], sel, mf, sreg, ge);
        scan_step<3, 4>(t0 + 1, lane, A4, KP, rb[1], sel, mf, sreg, ge);
        scan_step<3, 4>(t0 + 2, lane, A4, KP, rb[2], sel, mf, sreg, ge);
        scan_step<3, 4>(t0 + 3, lane, A4, KP, rb[3], sel, mf, sreg, ge);
    }
    for (int t0 = 767; t0 < 1023; t0 += 4) {          // 256 steps, NC=4
        scan_step<4, 4>(t0 + 0, lane, A4, KP, rb[0], sel, mf, sreg, ge);
        scan_step<4, 4>(t0 + 1, lane, A4, KP, rb[1], sel, mf, sreg, ge);
        scan_step<4, 4>(t0 + 2, lane, A4, KP, rb[2], sel, mf, sreg, ge);
        scan_step<4, 4>(t0 + 3, lane, A4, KP, rb[3], sel, mf, sreg, ge);
    }
}

// ---------------------------------------------------------------------------
// Fused mask + renorm + PV: ctx = (keep.*P) @ V / rowsum(keep.*P).
// Each 64-row tile spans the full causal row, so row sums are computed
// locally (redundantly across the x-grid) — removes the renorm kernel's
// full 256 MB R+W pass.
// ---------------------------------------------------------------------------
__global__ __launch_bounds__(256) void pv_renorm(const float* __restrict__ scores,
                                                 const unsigned char* __restrict__ keep,
                                                 const float* __restrict__ v,
                                                 unsigned short* __restrict__ ctxb)
{
    int bh = blockIdx.z;
    int b_ = bh / NHh, h_ = bh % NHh;
    const float* P = scores + (size_t)bh * Ss * Ss;
    const unsigned char* KPm = keep + (size_t)bh * Ss * Ss;
    const float* V = v + (size_t)bh * Ss * HDd;
    int bm = blockIdx.y * 64, bn = blockIdx.x * 64;
    int tid = threadIdx.x, tx = tid & 15, ty = tid >> 4;
    __shared__ float As[16][65];
    __shared__ float Bs[16][64];
    float acc[4][4] = {};
    float rs[4] = {};
    int kend = bm + 64;  // causal truncation (covers full causal row extent)
    for (int k0 = 0; k0 < kend; k0 += 16) {
#pragma unroll
        for (int l = 0; l < 4; ++l) {
            int idx = tid + l * 256;
            int r = idx >> 4, c = idx & 15;
            int row = bm + r;
            float p = P[(size_t)row * Ss + k0 + c];
            // rows <= CBc keep everything; raw P is exactly 0 above the
            // diagonal, so garbage keep bytes there are harmless.
            if (row > CBc && !KPm[(size_t)row * Ss + k0 + c]) p = 0.0f;
            As[c][r] = p;
        }
#pragma unroll
        for (int l = 0; l < 4; ++l) {
            int idx = tid + l * 256;
            int r = idx >> 6, c = idx & 63;
            Bs[r][c] = V[(size_t)(k0 + r) * HDd + bn + c];
        }
        __syncthreads();
#pragma unroll
        for (int kk = 0; kk < 16; ++kk) {
            float a[4], b[4];
#pragma unroll
            for (int i = 0; i < 4; ++i) a[i] = As[kk][ty * 4 + i];
#pragma unroll
            for (int j = 0; j < 4; ++j) b[j] = Bs[kk][tx * 4 + j];
#pragma unroll
            for (int i = 0; i < 4; ++i) rs[i] += a[i];
#pragma unroll
            for (int i = 0; i < 4; ++i)
#pragma unroll
                for (int j = 0; j < 4; ++j)
                    acc[i][j] = fmaf(a[i], b[j], acc[i][j]);
        }
        __syncthreads();
    }
#pragma unroll
    for (int i = 0; i < 4; ++i) {
        float inv = 1.0f / rs[i];   // rs > 0 (diagonal prob always kept)
        int sq = bm + ty * 4 + i;
#pragma unroll
        for (int j = 0; j < 4; ++j) {
            int d = bn + tx * 4 + j;
            ctxb[(size_t)(b_ * Ss + sq) * HIDd + h_ * HDd + d] = f2b(acc[i][j] * inv);
        }
    }
}

// ---------------------------------------------------------------------------
extern "C" void kernel_launch(void* const* d_in, const int* in_sizes, int n_in,
                              void* d_out, int out_size, void* d_ws, size_t ws_size,
                              hipStream_t stream)
{
    const float* hs = (const float*)d_in[0];
    const float* wq = (const float*)d_in[1];
    const float* wk = (const float*)d_in[2];
    const float* wv = (const float*)d_in[3];
    const float* wo = (const float*)d_in[4];
    float* out = (float*)d_out;

    float* ws = (float*)d_ws;
    size_t off = 0;
    float* qf   = ws + off; off += (size_t)NBH * Ss * HDd;   // 16 MB (reused: ctxb)
    float* kf   = ws + off; off += (size_t)NBH * Ss * HDd;   // 16 MB
    float* vf   = ws + off; off += (size_t)NBH * Ss * HDd;   // 16 MB
    float* attn = ws + off; off += (size_t)NBH * Ss * Ss;    // 128 MB
    unsigned char* keep = (unsigned char*)(ws + off); off += (size_t)NBH * Ss * Ss / 4; // 32 MB
    unsigned short* wot = (unsigned short*)(ws + off); off += (size_t)HIDd * HIDd / 2;  // 8 MB

    // Transients overlaid on attn (dead before attn is written). 8 MB = 2M floats each.
    unsigned short* hsh  = (unsigned short*)(attn);
    unsigned short* hsl  = (unsigned short*)(attn + 2u * 1024 * 1024);
    unsigned short* wqth = (unsigned short*)(attn + 4u * 1024 * 1024);
    unsigned short* wqtl = (unsigned short*)(attn + 6u * 1024 * 1024);
    unsigned short* wkth = (unsigned short*)(attn + 8u * 1024 * 1024);
    unsigned short* wktl = (unsigned short*)(attn + 10u * 1024 * 1024);
    unsigned short* wvt  = (unsigned short*)(attn + 12u * 1024 * 1024);
    // q/k split bf16 overlaid on keep (keep written only by the scan, later):
    unsigned short* qh = (unsigned short*)keep;
    unsigned short* ql = (unsigned short*)(keep + 8u * 1024 * 1024);
    unsigned short* kh = (unsigned short*)(keep + 16u * 1024 * 1024);
    unsigned short* kl = (unsigned short*)(keep + 24u * 1024 * 1024);
    // ctxb overlays qf (qf dead after rope):
    unsigned short* ctxb = (unsigned short*)qf;

    dim3 blk(256);
    const int M = Bb * Ss;  // 2048

    // hs -> split bf16
    conv_split<<<dim3((M * HIDd / 4 + 255) / 256), blk, 0, stream>>>(hs, hsh, hsl, M * HIDd / 4);

    // weight transposes
    dim3 gt(HIDd / 64, HIDd / 64);
    tconv_split<<<gt, blk, 0, stream>>>(wq, wqth, wqtl, HIDd, HIDd);
    tconv_split<<<gt, blk, 0, stream>>>(wk, wkth, wktl, HIDd, HIDd);
    tconv<<<gt, blk, 0, stream>>>(wv, wvt, HIDd, HIDd);
    tconv<<<gt, blk, 0, stream>>>(wo, wot, HIDd, HIDd);

    // projections: q,k split-precision MFMA; v single bf16 MFMA
    dim3 gp(HIDd / 128, M / 128);   // 16 x 16
    gemm_split<1><<<gp, blk, 0, stream>>>(hsh, hsl, wqth, wqtl, qf, M, HIDd, HIDd);
    gemm_split<1><<<gp, blk, 0, stream>>>(hsh, hsl, wkth, wktl, kf, M, HIDd, HIDd);
    gemm_bf16t<1><<<gp, blk, 0, stream>>>(hsh, wvt, vf, M, HIDd, HIDd);

    // RoPE (fp32 math) -> split bf16 q,k
    rope_qk_split<<<dim3(NBH * Ss), dim3(64), 0, stream>>>(qf, kf, qh, ql, kh, kl);

    // QK^T (split-precision MFMA) + causal mask
    attn_qk_split<<<dim3(Ss / 128, Ss / 128, NBH), blk, 0, stream>>>(qh, ql, kh, kl, attn);

    // attn -> normalized scores, in place
    softmax_rows<<<dim3(NROWS), blk, 0, stream>>>(attn);

    // sequential A2S scan -> keep mask (overwrites qh..kl region, now dead)
    scan_kernel6<<<dim3(NBH), dim3(64), 0, stream>>>(attn, keep);

    // fused mask + renorm + PV (fp32 math, bf16 out)
    pv_renorm<<<dim3(HDd / 64, Ss / 64, NBH), blk, 0, stream>>>(attn, keep, vf, ctxb);

    // out = ctx @ wo (bf16 MFMA, fp32 out)
    gemm_bf16t<0><<<gp, blk, 0, stream>>>(ctxb, wot, out, M, HIDd, HIDd);
}

// Round 3
// 1159.514 us; speedup vs baseline: 1.0273x; 1.0273x over previous
//
#include <hip/hip_runtime.h>
#include <math.h>

// Problem constants (from reference)
#define Bb    2
#define Ss    1024
#define HIDd  2048
#define NHh   16
#define HDd   128
#define SBc   20      // floor(0.02*1024+0.5)
#define SELBc 61      // floor(0.06*1024+0.5)
#define RBc   82      // floor(0.08*1024+0.5)
#define CBc   163     // SB+SELB+RB
#define FFf   0.9f
#define MASKVAL (-3.4028234663852886e38f)
#define NBH   (Bb*NHh)       // 32
#define NROWS (NBH*Ss)       // 32768

typedef __attribute__((ext_vector_type(8))) short short8;
typedef __attribute__((ext_vector_type(4))) float f32x4;

__device__ __forceinline__ unsigned short f2b(float f) {
    unsigned u = __float_as_uint(f);
    u = (u + 0x7FFFu + ((u >> 16) & 1u)) >> 16;   // RNE
    return (unsigned short)u;
}
__device__ __forceinline__ float b2f(unsigned short h) {
    return __uint_as_float((unsigned)h << 16);
}

// ---------------------------------------------------------------------------
// Async global->LDS direct DMA (16B/lane). LDS dest = wave-uniform base +
// lane*16 (hardware rule); all call sites below have tid-linear LDS layouts.
// ---------------------------------------------------------------------------
#if defined(__has_builtin)
#if __has_builtin(__builtin_amdgcn_global_load_lds)
#define USE_GLD 1
#endif
#endif

__device__ __forceinline__ void gload16(const void* g, void* l) {
#ifdef USE_GLD
    __builtin_amdgcn_global_load_lds(
        (const __attribute__((address_space(1))) void*)g,
        (__attribute__((address_space(3))) void*)l, 16, 0, 0);
#else
    *(short8*)l = *(const short8*)g;
#endif
}

// ---------------------------------------------------------------------------
// fp32 -> split bf16 (hi + lo). lo = bf16(x - fp32(hi)).
// ---------------------------------------------------------------------------
__global__ __launch_bounds__(256) void conv_split(const float* __restrict__ x,
                                                  unsigned short* __restrict__ yh,
                                                  unsigned short* __restrict__ yl, int n4)
{
    int i = blockIdx.x * 256 + threadIdx.x;
    if (i >= n4) return;
    float4 v = ((const float4*)x)[i];
    ushort4 h, l;
    h.x = f2b(v.x); l.x = f2b(v.x - b2f(h.x));
    h.y = f2b(v.y); l.y = f2b(v.y - b2f(h.y));
    h.z = f2b(v.z); l.z = f2b(v.z - b2f(h.z));
    h.w = f2b(v.w); l.w = f2b(v.w - b2f(h.w));
    ((ushort4*)yh)[i] = h;
    ((ushort4*)yl)[i] = l;
}

// ---------------------------------------------------------------------------
// Transpose + convert: W[k][n] fp32 -> Wt[n][k] bf16 (single).
// ---------------------------------------------------------------------------
__global__ __launch_bounds__(256) void tconv(const float* __restrict__ W,
                                             unsigned short* __restrict__ Wt,
                                             int Kdim, int Ndim)
{
    __shared__ float T[64][65];
    int n0 = blockIdx.x * 64, k0 = blockIdx.y * 64;
    int tid = threadIdx.x;
    int rr = tid >> 4, cc = (tid & 15) * 4;
#pragma unroll
    for (int p = 0; p < 4; ++p) {
        int r = rr + p * 16;
        float4 x = *(const float4*)&W[(size_t)(k0 + r) * Ndim + n0 + cc];
        T[r][cc] = x.x; T[r][cc + 1] = x.y; T[r][cc + 2] = x.z; T[r][cc + 3] = x.w;
    }
    __syncthreads();
#pragma unroll
    for (int p = 0; p < 4; ++p) {
        int rn = rr + p * 16;
        ushort4 o;
        o.x = f2b(T[cc][rn]);     o.y = f2b(T[cc + 1][rn]);
        o.z = f2b(T[cc + 2][rn]); o.w = f2b(T[cc + 3][rn]);
        *(ushort4*)&Wt[(size_t)(n0 + rn) * Kdim + k0 + cc] = o;
    }
}

// ---------------------------------------------------------------------------
// Transpose + split convert: W[k][n] fp32 -> Wth/Wtl[n][k] bf16 hi/lo.
// ---------------------------------------------------------------------------
__global__ __launch_bounds__(256) void tconv_split(const float* __restrict__ W,
                                                   unsigned short* __restrict__ Wth,
                                                   unsigned short* __restrict__ Wtl,
                                                   int Kdim, int Ndim)
{
    __shared__ float T[64][65];
    int n0 = blockIdx.x * 64, k0 = blockIdx.y * 64;
    int tid = threadIdx.x;
    int rr = tid >> 4, cc = (tid & 15) * 4;
#pragma unroll
    for (int p = 0; p < 4; ++p) {
        int r = rr + p * 16;
        float4 x = *(const float4*)&W[(size_t)(k0 + r) * Ndim + n0 + cc];
        T[r][cc] = x.x; T[r][cc + 1] = x.y; T[r][cc + 2] = x.z; T[r][cc + 3] = x.w;
    }
    __syncthreads();
#pragma unroll
    for (int p = 0; p < 4; ++p) {
        int rn = rr + p * 16;
        float v0 = T[cc][rn], v1 = T[cc + 1][rn], v2 = T[cc + 2][rn], v3 = T[cc + 3][rn];
        ushort4 h, l;
        h.x = f2b(v0); l.x = f2b(v0 - b2f(h.x));
        h.y = f2b(v1); l.y = f2b(v1 - b2f(h.y));
        h.z = f2b(v2); l.z = f2b(v2 - b2f(h.z));
        h.w = f2b(v3); l.w = f2b(v3 - b2f(h.w));
        *(ushort4*)&Wth[(size_t)(n0 + rn) * Kdim + k0 + cc] = h;
        *(ushort4*)&Wtl[(size_t)(n0 + rn) * Kdim + k0 + cc] = l;
    }
}

// ---------------------------------------------------------------------------
// Single-bf16 MFMA GEMM: C = A @ Bt^T. 128x128 tile, 4 waves, 4x4 frags.
// Staging via global_load_lds (LDS layout is tid-linear *16B).
// MODE 0: C[m*N+n].  MODE 1: qkv permute -> C[((b*NH+h)*S+s)*HD+d].
// ---------------------------------------------------------------------------
template<int MODE>
__global__ __launch_bounds__(256) void gemm_bf16t(const unsigned short* __restrict__ A,
                                                  const unsigned short* __restrict__ Bt,
                                                  float* __restrict__ C,
                                                  int M, int N, int K)
{
    __shared__ unsigned short As[128 * 32];
    __shared__ unsigned short Bs[128 * 32];
    const int tid = threadIdx.x;
    const int bm = blockIdx.y * 128, bn = blockIdx.x * 128;
    const int lane = tid & 63, wid = tid >> 6;
    const int wr = (wid >> 1) * 64, wc = (wid & 1) * 64;
    const int lm = lane & 15, lk = (lane >> 4) * 8;

    f32x4 acc[4][4];
#pragma unroll
    for (int mi = 0; mi < 4; ++mi)
#pragma unroll
        for (int ni = 0; ni < 4; ++ni) acc[mi][ni] = 0.0f;

    for (int k0 = 0; k0 < K; k0 += 32) {
#pragma unroll
        for (int l = 0; l < 2; ++l) {
            int L = tid + l * 256;
            int row = L >> 2, c8 = (L & 3) * 8;
            gload16(&A[(size_t)(bm + row) * K + k0 + c8], &As[L * 8]);
            gload16(&Bt[(size_t)(bn + row) * K + k0 + c8], &Bs[L * 8]);
        }
        __syncthreads();
        short8 af[4], bf[4];
#pragma unroll
        for (int mi = 0; mi < 4; ++mi) af[mi] = *(short8*)&As[(wr + mi * 16 + lm) * 32 + lk];
#pragma unroll
        for (int ni = 0; ni < 4; ++ni) bf[ni] = *(short8*)&Bs[(wc + ni * 16 + lm) * 32 + lk];
#pragma unroll
        for (int mi = 0; mi < 4; ++mi)
#pragma unroll
            for (int ni = 0; ni < 4; ++ni)
                acc[mi][ni] = __builtin_amdgcn_mfma_f32_16x16x32_bf16(af[mi], bf[ni], acc[mi][ni], 0, 0, 0);
        __syncthreads();
    }
    const int lr = (lane >> 4) * 4;  // C/D: col=lane&15, row=(lane>>4)*4+reg
#pragma unroll
    for (int mi = 0; mi < 4; ++mi)
#pragma unroll
        for (int ni = 0; ni < 4; ++ni)
#pragma unroll
            for (int r = 0; r < 4; ++r) {
                int m = bm + wr + mi * 16 + lr + r;
                int n = bn + wc + ni * 16 + lm;
                float vv = acc[mi][ni][r];
                if (MODE == 0) {
                    C[(size_t)m * N + n] = vv;
                } else {
                    int b_ = m / Ss, s_ = m % Ss;
                    int h_ = n / HDd, d_ = n % HDd;
                    C[(size_t)((b_ * NHh + h_) * Ss + s_) * HDd + d_] = vv;
                }
            }
}

// ---------------------------------------------------------------------------
// Split-bf16 MFMA GEMM (hi/lo): C = (Ah+Al) @ (Bh+Bl)^T, dropping Al*Bl.
// 3 MFMAs per fragment pair. Staging via global_load_lds.
// ---------------------------------------------------------------------------
template<int MODE>
__global__ __launch_bounds__(256) void gemm_split(const unsigned short* __restrict__ Ah,
                                                  const unsigned short* __restrict__ Al,
                                                  const unsigned short* __restrict__ Bh,
                                                  const unsigned short* __restrict__ Bl,
                                                  float* __restrict__ C,
                                                  int M, int N, int K)
{
    __shared__ unsigned short AsH[128 * 32], AsL[128 * 32];
    __shared__ unsigned short BsH[128 * 32], BsL[128 * 32];
    const int tid = threadIdx.x;
    const int bm = blockIdx.y * 128, bn = blockIdx.x * 128;
    const int lane = tid & 63, wid = tid >> 6;
    const int wr = (wid >> 1) * 64, wc = (wid & 1) * 64;
    const int lm = lane & 15, lk = (lane >> 4) * 8;

    f32x4 acc[4][4];
#pragma unroll
    for (int mi = 0; mi < 4; ++mi)
#pragma unroll
        for (int ni = 0; ni < 4; ++ni) acc[mi][ni] = 0.0f;

    for (int k0 = 0; k0 < K; k0 += 32) {
#pragma unroll
        for (int l = 0; l < 2; ++l) {
            int L = tid + l * 256;
            int row = L >> 2, c8 = (L & 3) * 8;
            size_t ga = (size_t)(bm + row) * K + k0 + c8;
            size_t gb = (size_t)(bn + row) * K + k0 + c8;
            gload16(&Ah[ga], &AsH[L * 8]);
            gload16(&Al[ga], &AsL[L * 8]);
            gload16(&Bh[gb], &BsH[L * 8]);
            gload16(&Bl[gb], &BsL[L * 8]);
        }
        __syncthreads();
        short8 ah[4], al[4], bh[4], bl[4];
#pragma unroll
        for (int mi = 0; mi < 4; ++mi) {
            ah[mi] = *(short8*)&AsH[(wr + mi * 16 + lm) * 32 + lk];
            al[mi] = *(short8*)&AsL[(wr + mi * 16 + lm) * 32 + lk];
        }
#pragma unroll
        for (int ni = 0; ni < 4; ++ni) {
            bh[ni] = *(short8*)&BsH[(wc + ni * 16 + lm) * 32 + lk];
            bl[ni] = *(short8*)&BsL[(wc + ni * 16 + lm) * 32 + lk];
        }
#pragma unroll
        for (int mi = 0; mi < 4; ++mi)
#pragma unroll
            for (int ni = 0; ni < 4; ++ni) {
                acc[mi][ni] = __builtin_amdgcn_mfma_f32_16x16x32_bf16(ah[mi], bh[ni], acc[mi][ni], 0, 0, 0);
                acc[mi][ni] = __builtin_amdgcn_mfma_f32_16x16x32_bf16(ah[mi], bl[ni], acc[mi][ni], 0, 0, 0);
                acc[mi][ni] = __builtin_amdgcn_mfma_f32_16x16x32_bf16(al[mi], bh[ni], acc[mi][ni], 0, 0, 0);
            }
        __syncthreads();
    }
    const int lr = (lane >> 4) * 4;
#pragma unroll
    for (int mi = 0; mi < 4; ++mi)
#pragma unroll
        for (int ni = 0; ni < 4; ++ni)
#pragma unroll
            for (int r = 0; r < 4; ++r) {
                int m = bm + wr + mi * 16 + lr + r;
                int n = bn + wc + ni * 16 + lm;
                float vv = acc[mi][ni][r];
                if (MODE == 0) {
                    C[(size_t)m * N + n] = vv;
                } else {
                    int b_ = m / Ss, s_ = m % Ss;
                    int h_ = n / HDd, d_ = n % HDd;
                    C[(size_t)((b_ * NHh + h_) * Ss + s_) * HDd + d_] = vv;
                }
            }
}

// ---------------------------------------------------------------------------
// RoPE (fp32 math) -> split bf16 q,k (hi/lo).
// ---------------------------------------------------------------------------
__global__ __launch_bounds__(64) void rope_qk_split(const float* __restrict__ q,
                                                    const float* __restrict__ k,
                                                    unsigned short* __restrict__ qh,
                                                    unsigned short* __restrict__ ql,
                                                    unsigned short* __restrict__ kh,
                                                    unsigned short* __restrict__ kl)
{
    int idx = blockIdx.x;          // bh*S + s
    int s = idx % Ss;
    int d = threadIdx.x;           // 0..63
    float inv = powf(10000.0f, -2.0f * (float)d / 128.0f);
    float fr = (float)s * inv;
    float c = cosf(fr), sn = sinf(fr);
    size_t base = (size_t)idx * HDd;
    float q1 = q[base + d], q2 = q[base + d + 64];
    float k1 = k[base + d], k2 = k[base + d + 64];
    float qa = q1 * c - q2 * sn, qbv = q2 * c + q1 * sn;
    float ka = k1 * c - k2 * sn, kbv = k2 * c + k1 * sn;
    unsigned short h;
    h = f2b(qa);  qh[base + d]      = h; ql[base + d]      = f2b(qa  - b2f(h));
    h = f2b(qbv); qh[base + d + 64] = h; ql[base + d + 64] = f2b(qbv - b2f(h));
    h = f2b(ka);  kh[base + d]      = h; kl[base + d]      = f2b(ka  - b2f(h));
    h = f2b(kbv); kh[base + d + 64] = h; kl[base + d + 64] = f2b(kbv - b2f(h));
}

// ---------------------------------------------------------------------------
// attn = q k^T / sqrt(HD) via split-bf16 MFMA, causal mask to MASKVAL.
// ---------------------------------------------------------------------------
__global__ __launch_bounds__(256) void attn_qk_split(const unsigned short* __restrict__ qh,
                                                     const unsigned short* __restrict__ ql,
                                                     const unsigned short* __restrict__ kh,
                                                     const unsigned short* __restrict__ kl,
                                                     float* __restrict__ attn)
{
    const int bh = blockIdx.z;
    const int bm = blockIdx.y * 128, bn = blockIdx.x * 128;
    float* C = attn + (size_t)bh * Ss * Ss;
    const int tid = threadIdx.x;

    if (blockIdx.x > blockIdx.y) {  // fully above diagonal
        float4 mv = make_float4(MASKVAL, MASKVAL, MASKVAL, MASKVAL);
#pragma unroll
        for (int i = 0; i < 16; ++i) {
            int L = tid + i * 256;
            int row = L >> 5, c4 = (L & 31) * 4;
            *(float4*)&C[(size_t)(bm + row) * Ss + bn + c4] = mv;
        }
        return;
    }
    const size_t hb = (size_t)bh * Ss * HDd;
    const unsigned short* Ah = qh + hb;
    const unsigned short* Al = ql + hb;
    const unsigned short* Bh = kh + hb;
    const unsigned short* Bl = kl + hb;

    __shared__ unsigned short AsH[128 * 32], AsL[128 * 32];
    __shared__ unsigned short BsH[128 * 32], BsL[128 * 32];
    const int lane = tid & 63, wid = tid >> 6;
    const int wr = (wid >> 1) * 64, wc = (wid & 1) * 64;
    const int lm = lane & 15, lk = (lane >> 4) * 8;

    f32x4 acc[4][4];
#pragma unroll
    for (int mi = 0; mi < 4; ++mi)
#pragma unroll
        for (int ni = 0; ni < 4; ++ni) acc[mi][ni] = 0.0f;

    for (int k0 = 0; k0 < HDd; k0 += 32) {
#pragma unroll
        for (int l = 0; l < 2; ++l) {
            int L = tid + l * 256;
            int row = L >> 2, c8 = (L & 3) * 8;
            size_t ga = (size_t)(bm + row) * HDd + k0 + c8;
            size_t gb = (size_t)(bn + row) * HDd + k0 + c8;
            gload16(&Ah[ga], &AsH[L * 8]);
            gload16(&Al[ga], &AsL[L * 8]);
            gload16(&Bh[gb], &BsH[L * 8]);
            gload16(&Bl[gb], &BsL[L * 8]);
        }
        __syncthreads();
        short8 ah[4], al[4], bh2[4], bl2[4];
#pragma unroll
        for (int mi = 0; mi < 4; ++mi) {
            ah[mi] = *(short8*)&AsH[(wr + mi * 16 + lm) * 32 + lk];
            al[mi] = *(short8*)&AsL[(wr + mi * 16 + lm) * 32 + lk];
        }
#pragma unroll
        for (int ni = 0; ni < 4; ++ni) {
            bh2[ni] = *(short8*)&BsH[(wc + ni * 16 + lm) * 32 + lk];
            bl2[ni] = *(short8*)&BsL[(wc + ni * 16 + lm) * 32 + lk];
        }
#pragma unroll
        for (int mi = 0; mi < 4; ++mi)
#pragma unroll
            for (int ni = 0; ni < 4; ++ni) {
                acc[mi][ni] = __builtin_amdgcn_mfma_f32_16x16x32_bf16(ah[mi], bh2[ni], acc[mi][ni], 0, 0, 0);
                acc[mi][ni] = __builtin_amdgcn_mfma_f32_16x16x32_bf16(ah[mi], bl2[ni], acc[mi][ni], 0, 0, 0);
                acc[mi][ni] = __builtin_amdgcn_mfma_f32_16x16x32_bf16(al[mi], bh2[ni], acc[mi][ni], 0, 0, 0);
            }
        __syncthreads();
    }
    const float scale = 0.08838834764831845f;  // 1/sqrt(128)
    const int lr = (lane >> 4) * 4;
#pragma unroll
    for (int mi = 0; mi < 4; ++mi)
#pragma unroll
        for (int ni = 0; ni < 4; ++ni)
#pragma unroll
            for (int r = 0; r < 4; ++r) {
                int sq = bm + wr + mi * 16 + lr + r;
                int sk = bn + wc + ni * 16 + lm;
                C[(size_t)sq * Ss + sk] = (sk <= sq) ? acc[mi][ni][r] * scale : MASKVAL;
            }
}

// ---------------------------------------------------------------------------
// Row softmax IN PLACE: attn -> scores = exp(a - rowmax) / rowsum.
// ---------------------------------------------------------------------------
__global__ __launch_bounds__(256) void softmax_rows(float* __restrict__ attn)
{
    int row = blockIdx.x;
    float4* a4 = (float4*)(attn + (size_t)row * Ss);
    int tid = threadIdx.x;
    float4 x = a4[tid];
    float m = fmaxf(fmaxf(x.x, x.y), fmaxf(x.z, x.w));
#pragma unroll
    for (int off = 32; off; off >>= 1) m = fmaxf(m, __shfl_xor(m, off));
    __shared__ float red[4];
    if ((tid & 63) == 0) red[tid >> 6] = m;
    __syncthreads();
    float mm = fmaxf(fmaxf(red[0], red[1]), fmaxf(red[2], red[3]));
    float e0 = expf(x.x - mm), e1 = expf(x.y - mm);
    float e2 = expf(x.z - mm), e3 = expf(x.w - mm);
    float s = e0 + e1 + e2 + e3;
#pragma unroll
    for (int off = 32; off; off >>= 1) s += __shfl_xor(s, off);
    __shared__ float red2[4];
    if ((tid & 63) == 0) red2[tid >> 6] = s;
    __syncthreads();
    float inv = 1.0f / (red2[0] + red2[1] + red2[2] + red2[3]);
    a4[tid] = make_float4(e0 * inv, e1 * inv, e2 * inv, e3 * inv);
}

// ---------------------------------------------------------------------------
// DPP cross-lane helpers (VALU-latency, no LDS pipe).
// ---------------------------------------------------------------------------
template<int CTRL>
__device__ __forceinline__ int dpp_i(int x) {
    return __builtin_amdgcn_update_dpp(0, x, CTRL, 0xF, 0xF, true);
}
__device__ __forceinline__ float wave_sum64(float x) {
    x += __int_as_float(dpp_i<0xB1>(__float_as_int(x)));
    x += __int_as_float(dpp_i<0x4E>(__float_as_int(x)));
    x += __int_as_float(dpp_i<0x141>(__float_as_int(x)));
    x += __int_as_float(dpp_i<0x140>(__float_as_int(x)));
    int xi = __float_as_int(x);
    float a = __int_as_float(__builtin_amdgcn_readlane(xi, 0));
    float b = __int_as_float(__builtin_amdgcn_readlane(xi, 16));
    float c = __int_as_float(__builtin_amdgcn_readlane(xi, 32));
    float d = __int_as_float(__builtin_amdgcn_readlane(xi, 48));
    return (a + c) + (b + d);
}

// 64-bit packed-key (value<<32 | index) helpers: lexicographic min == exact
// float-min with first-index tie-break (values are non-negative floats).
__device__ __forceinline__ unsigned long long u64min(unsigned long long a, unsigned long long b) {
    return a < b ? a : b;
}
template<int CTRL>
__device__ __forceinline__ unsigned long long dpp64(unsigned long long x) {
    int lo = (int)(unsigned)x;
    int hi = (int)(unsigned)(x >> 32);
    unsigned l2 = (unsigned)dpp_i<CTRL>(lo);
    unsigned h2 = (unsigned)dpp_i<CTRL>(hi);
    return ((unsigned long long)h2 << 32) | (unsigned long long)l2;
}
__device__ __forceinline__ unsigned long long wave_min64k(unsigned long long x) {
    x = u64min(x, dpp64<0xB1>(x));
    x = u64min(x, dpp64<0x4E>(x));
    x = u64min(x, dpp64<0x141>(x));
    x = u64min(x, dpp64<0x140>(x));
    int lo = (int)(unsigned)x;
    int hi = (int)(unsigned)(x >> 32);
    unsigned long long a = ((unsigned long long)(unsigned)__builtin_amdgcn_readlane(hi, 0)  << 32) |
                           (unsigned long long)(unsigned)__builtin_amdgcn_readlane(lo, 0);
    unsigned long long b = ((unsigned long long)(unsigned)__builtin_amdgcn_readlane(hi, 16) << 32) |
                           (unsigned long long)(unsigned)__builtin_amdgcn_readlane(lo, 16);
    unsigned long long c = ((unsigned long long)(unsigned)__builtin_amdgcn_readlane(hi, 32) << 32) |
                           (unsigned long long)(unsigned)__builtin_amdgcn_readlane(lo, 32);
    unsigned long long d = ((unsigned long long)(unsigned)__builtin_amdgcn_readlane(hi, 48) << 32) |
                           (unsigned long long)(unsigned)__builtin_amdgcn_readlane(lo, 48);
    return u64min(u64min(a, b), u64min(c, d));
}

__device__ __forceinline__ float f4c(float4 v, int i) {
    return i == 0 ? v.x : (i == 1 ? v.y : (i == 2 ? v.z : v.w));
}

// ---------------------------------------------------------------------------
// A2S sequential scan v7: TWO waves per chain (128-thread block).
// Wave0 owns chunks {0,2}, wave1 owns {1,3}. Per step, each wave does the
// v5-style branchless work on its (compile-time) chunk set; the two wave-
// local reductions (sum, min-key) are combined via 2 LDS slots + barrier.
// All chunk-set/phase control flow is template-resolved — no runtime
// branches inside the step (R2 lesson).
// Exactness: tot = wsum(w0) + wsum(w1) changes the fp add tree vs v5; the
// min-key combine is order-independent (exact min + first-index tiebreak).
// ---------------------------------------------------------------------------
template<int C0, int C1, int WID, bool A0, bool A1, bool P0, bool P1>
__device__ __forceinline__ void scan_step7(int t, int lane,
                                           const float4* __restrict__ A4,
                                           unsigned char* __restrict__ KP,
                                           float4 (&rb)[2],
                                           float (&sel)[2][4],
                                           float (&mf)[2][4],
                                           float* lds_sum,
                                           unsigned long long* lds_min,
                                           bool ge)
{
    const float INFv = __int_as_float(0x7f800000);
    float4 a0 = make_float4(0.f, 0.f, 0.f, 0.f);
    float4 a1 = make_float4(0.f, 0.f, 0.f, 0.f);
    if (A0) a0 = rb[0];
    if (A1) a1 = rb[1];
    int tp = t + 4; if (tp > Ss - 1) tp = Ss - 1;
    if (P0) rb[0] = A4[tp * 256 + C0 * 64 + lane];
    if (P1) rb[1] = A4[tp * 256 + C1 * 64 + lane];

    // masked row sum over own chunks (ascending chunk id)
    if (A0 || A1) {
        float lsum = 0.0f;
        if (A0) lsum += (a0.x * mf[0][0] + a0.y * mf[0][1]) + (a0.z * mf[0][2] + a0.w * mf[0][3]);
        if (A1) lsum += (a1.x * mf[1][0] + a1.y * mf[1][1]) + (a1.z * mf[1][2] + a1.w * mf[1][3]);
        float wsv = wave_sum64(lsum);
        if (lane == 0) lds_sum[WID] = wsv;
    } else {
        if (lane == 0) lds_sum[WID] = 0.0f;
    }
    __syncthreads();
    float tot = lds_sum[0] + lds_sum[1];
    float inv = 1.0f / tot;

    const int local = t - RBc;

    // sel update + windowed argmin via packed (value,index) keys
    unsigned long long kmin = ~0ull;
    if (A0) {
        unsigned long long kk[4];
#pragma unroll
        for (int i = 0; i < 4; ++i) {
            float sv = fmaf(FFf, sel[0][i], f4c(a0, i) * inv);
            sel[0][i] = sv;
            int s = C0 * 256 + lane * 4 + i;
            bool win = (s <= local) && (C0 > 0 || ge);
            unsigned hi = win ? __float_as_uint(sv) : 0x7f800000u;
            kk[i] = ((unsigned long long)hi << 32) | (unsigned long long)(unsigned)s;
        }
        kmin = u64min(kmin, u64min(u64min(kk[0], kk[1]), u64min(kk[2], kk[3])));
    }
    if (A1) {
        unsigned long long kk[4];
#pragma unroll
        for (int i = 0; i < 4; ++i) {
            float sv = fmaf(FFf, sel[1][i], f4c(a1, i) * inv);
            sel[1][i] = sv;
            int s = C1 * 256 + lane * 4 + i;
            bool win = (s <= local);   // C1 >= 2 -> always past SBc
            unsigned hi = win ? __float_as_uint(sv) : 0x7f800000u;
            kk[i] = ((unsigned long long)hi << 32) | (unsigned long long)(unsigned)s;
        }
        kmin = u64min(kmin, u64min(u64min(kk[0], kk[1]), u64min(kk[2], kk[3])));
    }
    if (A0 || A1) {
        kmin = wave_min64k(kmin);
        if (lane == 0) lds_min[WID] = kmin;
    } else {
        if (lane == 0) lds_min[WID] = ~0ull;
    }
    __syncthreads();
    unsigned long long kall = u64min(lds_min[0], lds_min[1]);
    const int besti = (int)(unsigned)(kall & 0xFFFFFFFFull);

    // evict (v5-style branchless vector compare on own chunks)
    if (A0) {
#pragma unroll
        for (int i = 0; i < 4; ++i) {
            int s = C0 * 256 + lane * 4 + i;
            bool e = (s == besti);
            sel[0][i] = e ? INFv : sel[0][i];
            mf[0][i]  = e ? 0.0f : mf[0][i];
        }
    }
    if (A1) {
#pragma unroll
        for (int i = 0; i < 4; ++i) {
            int s = C1 * 256 + lane * 4 + i;
            bool e = (s == besti);
            sel[1][i] = e ? INFv : sel[1][i];
            mf[1][i]  = e ? 0.0f : mf[1][i];
        }
    }

    // keep row t+1 (own active chunks; scores are exactly 0 above diag)
    uchar4* kp4 = (uchar4*)(KP + (size_t)(t + 1) * Ss);
    if (A0) {
        uchar4 kb;
        kb.x = (unsigned char)mf[0][0];
        kb.y = (unsigned char)mf[0][1];
        kb.z = (unsigned char)mf[0][2];
        kb.w = (unsigned char)mf[0][3];
        kp4[C0 * 64 + lane] = kb;
    }
    if (A1) {
        uchar4 kb;
        kb.x = (unsigned char)mf[1][0];
        kb.y = (unsigned char)mf[1][1];
        kb.z = (unsigned char)mf[1][2];
        kb.w = (unsigned char)mf[1][3];
        kp4[C1 * 64 + lane] = kb;
    }
}

template<int WID>
__device__ __forceinline__ void scan_chain7(int lane,
                                            const float4* __restrict__ A4,
                                            unsigned char* __restrict__ KP,
                                            float* lds_sum,
                                            unsigned long long* lds_min)
{
    constexpr int C0 = WID;        // 0 or 1
    constexpr int C1 = WID + 2;    // 2 or 3
    float sel[2][4], mf[2][4];
#pragma unroll
    for (int j = 0; j < 2; ++j)
#pragma unroll
        for (int i = 0; i < 4; ++i) { sel[j][i] = 0.0f; mf[j][i] = 1.0f; }
    const bool ge = (lane * 4 >= SBc);   // only relevant for chunk 0

    if (WID == 0) {
        // warmup rows 0..162: chunk 0 only (rows <163 are zero beyond col 162)
        float4 w0 = A4[0 * 256 + lane];
        float4 w1 = A4[1 * 256 + lane];
        float4 w2 = A4[2 * 256 + lane];
        float4 w3 = A4[3 * 256 + lane];
#define WSTEP(W, NEXT)                                                       \
        do {                                                                 \
            float4 _a = W;                                                   \
            W = A4[(NEXT) * 256 + lane];                                     \
            sel[0][0] = fmaf(FFf, sel[0][0], _a.x);                          \
            sel[0][1] = fmaf(FFf, sel[0][1], _a.y);                          \
            sel[0][2] = fmaf(FFf, sel[0][2], _a.z);                          \
            sel[0][3] = fmaf(FFf, sel[0][3], _a.w);                          \
        } while (0)
        for (int r = 0; r < 160; r += 4) {
            WSTEP(w0, r + 4); WSTEP(w1, r + 5); WSTEP(w2, r + 6); WSTEP(w3, r + 7);
        }
#undef WSTEP
        {   // rows 160..162 tail (w3 = row 163 discarded)
            float4 tl[3] = { w0, w1, w2 };
#pragma unroll
            for (int u = 0; u < 3; ++u) {
                sel[0][0] = fmaf(FFf, sel[0][0], tl[u].x);
                sel[0][1] = fmaf(FFf, sel[0][1], tl[u].y);
                sel[0][2] = fmaf(FFf, sel[0][2], tl[u].z);
                sel[0][3] = fmaf(FFf, sel[0][3], tl[u].w);
            }
        }
    }

    // initial prefetch: rows 163..166, own low chunk (C0)
    float4 rb[4][2];
#pragma unroll
    for (int slot = 0; slot < 4; ++slot) {
        rb[slot][0] = A4[(163 + slot) * 256 + C0 * 64 + lane];
        rb[slot][1] = make_float4(0.f, 0.f, 0.f, 0.f);
    }

    // Phase 1: t in [163,255). chunk0 active (wave0); wave1 prefetches c1.
    for (int t0 = 163; t0 < 255; t0 += 4) {
        scan_step7<C0, C1, WID, (WID == 0), false, true, false>(t0 + 0, lane, A4, KP, rb[0], sel, mf, lds_sum, lds_min, ge);
        scan_step7<C0, C1, WID, (WID == 0), false, true, false>(t0 + 1, lane, A4, KP, rb[1], sel, mf, lds_sum, lds_min, ge);
        scan_step7<C0, C1, WID, (WID == 0), false, true, false>(t0 + 2, lane, A4, KP, rb[2], sel, mf, lds_sum, lds_min, ge);
        scan_step7<C0, C1, WID, (WID == 0), false, true, false>(t0 + 3, lane, A4, KP, rb[3], sel, mf, lds_sum, lds_min, ge);
    }
    // Phase 2: t in [255,511). chunks {0,1} active; wave0 prefetches c2.
    for (int t0 = 255; t0 < 511; t0 += 4) {
        scan_step7<C0, C1, WID, true, false, true, (WID == 0)>(t0 + 0, lane, A4, KP, rb[0], sel, mf, lds_sum, lds_min, ge);
        scan_step7<C0, C1, WID, true, false, true, (WID == 0)>(t0 + 1, lane, A4, KP, rb[1], sel, mf, lds_sum, lds_min, ge);
        scan_step7<C0, C1, WID, true, false, true, (WID == 0)>(t0 + 2, lane, A4, KP, rb[2], sel, mf, lds_sum, lds_min, ge);
        scan_step7<C0, C1, WID, true, false, true, (WID == 0)>(t0 + 3, lane, A4, KP, rb[3], sel, mf, lds_sum, lds_min, ge);
    }
    // Phase 3: t in [511,767). chunks {0,1,2} active; wave1 prefetches c3.
    for (int t0 = 511; t0 < 767; t0 += 4) {
        scan_step7<C0, C1, WID, true, (WID == 0), true, true>(t0 + 0, lane, A4, KP, rb[0], sel, mf, lds_sum, lds_min, ge);
        scan_step7<C0, C1, WID, true, (WID == 0), true, true>(t0 + 1, lane, A4, KP, rb[1], sel, mf, lds_sum, lds_min, ge);
        scan_step7<C0, C1, WID, true, (WID == 0), true, true>(t0 + 2, lane, A4, KP, rb[2], sel, mf, lds_sum, lds_min, ge);
        scan_step7<C0, C1, WID, true, (WID == 0), true, true>(t0 + 3, lane, A4, KP, rb[3], sel, mf, lds_sum, lds_min, ge);
    }
    // Phase 4: t in [767,1023). all chunks active.
    for (int t0 = 767; t0 < 1023; t0 += 4) {
        scan_step7<C0, C1, WID, true, true, true, true>(t0 + 0, lane, A4, KP, rb[0], sel, mf, lds_sum, lds_min, ge);
        scan_step7<C0, C1, WID, true, true, true, true>(t0 + 1, lane, A4, KP, rb[1], sel, mf, lds_sum, lds_min, ge);
        scan_step7<C0, C1, WID, true, true, true, true>(t0 + 2, lane, A4, KP, rb[2], sel, mf, lds_sum, lds_min, ge);
        scan_step7<C0, C1, WID, true, true, true, true>(t0 + 3, lane, A4, KP, rb[3], sel, mf, lds_sum, lds_min, ge);
    }
}

__global__ __launch_bounds__(128) void scan_kernel7(const float* __restrict__ scores,
                                                    unsigned char* __restrict__ keep)
{
    __shared__ float lds_sum[2];
    __shared__ unsigned long long lds_min[2];
    int bh = blockIdx.x;
    int tid = threadIdx.x;
    int lane = tid & 63, wid = tid >> 6;
    const float4* A4 = (const float4*)(scores + (size_t)bh * Ss * Ss);
    unsigned char* KP = keep + (size_t)bh * Ss * Ss;
    if (wid == 0) scan_chain7<0>(lane, A4, KP, lds_sum, lds_min);
    else          scan_chain7<1>(lane, A4, KP, lds_sum, lds_min);
}

// ---------------------------------------------------------------------------
// Fused mask + renorm + PV: ctx = (keep.*P) @ V / rowsum(keep.*P).
// ---------------------------------------------------------------------------
__global__ __launch_bounds__(256) void pv_renorm(const float* __restrict__ scores,
                                                 const unsigned char* __restrict__ keep,
                                                 const float* __restrict__ v,
                                                 unsigned short* __restrict__ ctxb)
{
    int bh = blockIdx.z;
    int b_ = bh / NHh, h_ = bh % NHh;
    const float* P = scores + (size_t)bh * Ss * Ss;
    const unsigned char* KPm = keep + (size_t)bh * Ss * Ss;
    const float* V = v + (size_t)bh * Ss * HDd;
    int bm = blockIdx.y * 64, bn = blockIdx.x * 64;
    int tid = threadIdx.x, tx = tid & 15, ty = tid >> 4;
    __shared__ float As[16][65];
    __shared__ float Bs[16][64];
    float acc[4][4] = {};
    float rs[4] = {};
    int kend = bm + 64;  // causal truncation (covers full causal row extent)
    for (int k0 = 0; k0 < kend; k0 += 16) {
#pragma unroll
        for (int l = 0; l < 4; ++l) {
            int idx = tid + l * 256;
            int r = idx >> 4, c = idx & 15;
            int row = bm + r;
            float p = P[(size_t)row * Ss + k0 + c];
            if (row > CBc && !KPm[(size_t)row * Ss + k0 + c]) p = 0.0f;
            As[c][r] = p;
        }
#pragma unroll
        for (int l = 0; l < 4; ++l) {
            int idx = tid + l * 256;
            int r = idx >> 6, c = idx & 63;
            Bs[r][c] = V[(size_t)(k0 + r) * HDd + bn + c];
        }
        __syncthreads();
#pragma unroll
        for (int kk = 0; kk < 16; ++kk) {
            float a[4], b[4];
#pragma unroll
            for (int i = 0; i < 4; ++i) a[i] = As[kk][ty * 4 + i];
#pragma unroll
            for (int j = 0; j < 4; ++j) b[j] = Bs[kk][tx * 4 + j];
#pragma unroll
            for (int i = 0; i < 4; ++i) rs[i] += a[i];
#pragma unroll
            for (int i = 0; i < 4; ++i)
#pragma unroll
                for (int j = 0; j < 4; ++j)
                    acc[i][j] = fmaf(a[i], b[j], acc[i][j]);
        }
        __syncthreads();
    }
#pragma unroll
    for (int i = 0; i < 4; ++i) {
        float inv = 1.0f / rs[i];   // rs > 0 (diagonal prob always kept)
        int sq = bm + ty * 4 + i;
#pragma unroll
        for (int j = 0; j < 4; ++j) {
            int d = bn + tx * 4 + j;
            ctxb[(size_t)(b_ * Ss + sq) * HIDd + h_ * HDd + d] = f2b(acc[i][j] * inv);
        }
    }
}

// ---------------------------------------------------------------------------
extern "C" void kernel_launch(void* const* d_in, const int* in_sizes, int n_in,
                              void* d_out, int out_size, void* d_ws, size_t ws_size,
                              hipStream_t stream)
{
    const float* hs = (const float*)d_in[0];
    const float* wq = (const float*)d_in[1];
    const float* wk = (const float*)d_in[2];
    const float* wv = (const float*)d_in[3];
    const float* wo = (const float*)d_in[4];
    float* out = (float*)d_out;

    float* ws = (float*)d_ws;
    size_t off = 0;
    float* qf   = ws + off; off += (size_t)NBH * Ss * HDd;   // 16 MB (reused: ctxb)
    float* kf   = ws + off; off += (size_t)NBH * Ss * HDd;   // 16 MB
    float* vf   = ws + off; off += (size_t)NBH * Ss * HDd;   // 16 MB
    float* attn = ws + off; off += (size_t)NBH * Ss * Ss;    // 128 MB
    unsigned char* keep = (unsigned char*)(ws + off); off += (size_t)NBH * Ss * Ss / 4; // 32 MB
    unsigned short* wot = (unsigned short*)(ws + off); off += (size_t)HIDd * HIDd / 2;  // 8 MB

    // Transients overlaid on attn (dead before attn is written). 8 MB = 2M floats each.
    unsigned short* hsh  = (unsigned short*)(attn);
    unsigned short* hsl  = (unsigned short*)(attn + 2u * 1024 * 1024);
    unsigned short* wqth = (unsigned short*)(attn + 4u * 1024 * 1024);
    unsigned short* wqtl = (unsigned short*)(attn + 6u * 1024 * 1024);
    unsigned short* wkth = (unsigned short*)(attn + 8u * 1024 * 1024);
    unsigned short* wktl = (unsigned short*)(attn + 10u * 1024 * 1024);
    unsigned short* wvt  = (unsigned short*)(attn + 12u * 1024 * 1024);
    // q/k split bf16 overlaid on keep (keep written only by the scan, later):
    unsigned short* qh = (unsigned short*)keep;
    unsigned short* ql = (unsigned short*)(keep + 8u * 1024 * 1024);
    unsigned short* kh = (unsigned short*)(keep + 16u * 1024 * 1024);
    unsigned short* kl = (unsigned short*)(keep + 24u * 1024 * 1024);
    // ctxb overlays qf (qf dead after rope):
    unsigned short* ctxb = (unsigned short*)qf;

    dim3 blk(256);
    const int M = Bb * Ss;  // 2048

    // hs -> split bf16
    conv_split<<<dim3((M * HIDd / 4 + 255) / 256), blk, 0, stream>>>(hs, hsh, hsl, M * HIDd / 4);

    // weight transposes
    dim3 gt(HIDd / 64, HIDd / 64);
    tconv_split<<<gt, blk, 0, stream>>>(wq, wqth, wqtl, HIDd, HIDd);
    tconv_split<<<gt, blk, 0, stream>>>(wk, wkth, wktl, HIDd, HIDd);
    tconv<<<gt, blk, 0, stream>>>(wv, wvt, HIDd, HIDd);
    tconv<<<gt, blk, 0, stream>>>(wo, wot, HIDd, HIDd);

    // projections: q,k split-precision MFMA; v single bf16 MFMA
    dim3 gp(HIDd / 128, M / 128);   // 16 x 16
    gemm_split<1><<<gp, blk, 0, stream>>>(hsh, hsl, wqth, wqtl, qf, M, HIDd, HIDd);
    gemm_split<1><<<gp, blk, 0, stream>>>(hsh, hsl, wkth, wktl, kf, M, HIDd, HIDd);
    gemm_bf16t<1><<<gp, blk, 0, stream>>>(hsh, wvt, vf, M, HIDd, HIDd);

    // RoPE (fp32 math) -> split bf16 q,k
    rope_qk_split<<<dim3(NBH * Ss), dim3(64), 0, stream>>>(qf, kf, qh, ql, kh, kl);

    // QK^T (split-precision MFMA) + causal mask
    attn_qk_split<<<dim3(Ss / 128, Ss / 128, NBH), blk, 0, stream>>>(qh, ql, kh, kl, attn);

    // attn -> normalized scores, in place
    softmax_rows<<<dim3(NROWS), blk, 0, stream>>>(attn);

    // sequential A2S scan (2 waves per chain) -> keep mask
    scan_kernel7<<<dim3(NBH), dim3(128), 0, stream>>>(attn, keep);

    // fused mask + renorm + PV (fp32 math, bf16 out)
    pv_renorm<<<dim3(HDd / 64, Ss / 64, NBH), blk, 0, stream>>>(attn, keep, vf, ctxb);

    // out = ctx @ wo (bf16 MFMA, fp32 out)
    gemm_bf16t<0><<<gp, blk, 0, stream>>>(ctxb, wot, out, M, HIDd, HIDd);
}

// Round 4
// 1053.395 us; speedup vs baseline: 1.1308x; 1.1007x over previous
//
#include <hip/hip_runtime.h>
#include <math.h>

// Problem constants (from reference)
#define Bb    2
#define Ss    1024
#define HIDd  2048
#define NHh   16
#define HDd   128
#define SBc   20      // floor(0.02*1024+0.5)
#define SELBc 61      // floor(0.06*1024+0.5)
#define RBc   82      // floor(0.08*1024+0.5)
#define CBc   163     // SB+SELB+RB
#define FFf   0.9f
#define MASKVAL (-3.4028234663852886e38f)
#define NBH   (Bb*NHh)       // 32
#define NROWS (NBH*Ss)       // 32768

typedef __attribute__((ext_vector_type(8))) short short8;
typedef __attribute__((ext_vector_type(4))) float f32x4;
typedef __attribute__((ext_vector_type(2))) float f32x2;

__device__ __forceinline__ unsigned short f2b(float f) {
    unsigned u = __float_as_uint(f);
    u = (u + 0x7FFFu + ((u >> 16) & 1u)) >> 16;   // RNE
    return (unsigned short)u;
}
__device__ __forceinline__ float b2f(unsigned short h) {
    return __uint_as_float((unsigned)h << 16);
}

// ---------------------------------------------------------------------------
// Async global->LDS direct DMA (16B/lane). LDS dest = wave-uniform base +
// lane*16 (hardware rule); all call sites below have tid-linear LDS layouts.
// ---------------------------------------------------------------------------
#if defined(__has_builtin)
#if __has_builtin(__builtin_amdgcn_global_load_lds)
#define USE_GLD 1
#endif
#endif

__device__ __forceinline__ void gload16(const void* g, void* l) {
#ifdef USE_GLD
    __builtin_amdgcn_global_load_lds(
        (const __attribute__((address_space(1))) void*)g,
        (__attribute__((address_space(3))) void*)l, 16, 0, 0);
#else
    *(short8*)l = *(const short8*)g;
#endif
}

// ---------------------------------------------------------------------------
// fp32 -> split bf16 (hi + lo). lo = bf16(x - fp32(hi)).
// ---------------------------------------------------------------------------
__global__ __launch_bounds__(256) void conv_split(const float* __restrict__ x,
                                                  unsigned short* __restrict__ yh,
                                                  unsigned short* __restrict__ yl, int n4)
{
    int i = blockIdx.x * 256 + threadIdx.x;
    if (i >= n4) return;
    float4 v = ((const float4*)x)[i];
    ushort4 h, l;
    h.x = f2b(v.x); l.x = f2b(v.x - b2f(h.x));
    h.y = f2b(v.y); l.y = f2b(v.y - b2f(h.y));
    h.z = f2b(v.z); l.z = f2b(v.z - b2f(h.z));
    h.w = f2b(v.w); l.w = f2b(v.w - b2f(h.w));
    ((ushort4*)yh)[i] = h;
    ((ushort4*)yl)[i] = l;
}

// ---------------------------------------------------------------------------
// Transpose + convert: W[k][n] fp32 -> Wt[n][k] bf16 (single).
// ---------------------------------------------------------------------------
__global__ __launch_bounds__(256) void tconv(const float* __restrict__ W,
                                             unsigned short* __restrict__ Wt,
                                             int Kdim, int Ndim)
{
    __shared__ float T[64][65];
    int n0 = blockIdx.x * 64, k0 = blockIdx.y * 64;
    int tid = threadIdx.x;
    int rr = tid >> 4, cc = (tid & 15) * 4;
#pragma unroll
    for (int p = 0; p < 4; ++p) {
        int r = rr + p * 16;
        float4 x = *(const float4*)&W[(size_t)(k0 + r) * Ndim + n0 + cc];
        T[r][cc] = x.x; T[r][cc + 1] = x.y; T[r][cc + 2] = x.z; T[r][cc + 3] = x.w;
    }
    __syncthreads();
#pragma unroll
    for (int p = 0; p < 4; ++p) {
        int rn = rr + p * 16;
        ushort4 o;
        o.x = f2b(T[cc][rn]);     o.y = f2b(T[cc + 1][rn]);
        o.z = f2b(T[cc + 2][rn]); o.w = f2b(T[cc + 3][rn]);
        *(ushort4*)&Wt[(size_t)(n0 + rn) * Kdim + k0 + cc] = o;
    }
}

// ---------------------------------------------------------------------------
// Transpose + split convert: W[k][n] fp32 -> Wth/Wtl[n][k] bf16 hi/lo.
// ---------------------------------------------------------------------------
__global__ __launch_bounds__(256) void tconv_split(const float* __restrict__ W,
                                                   unsigned short* __restrict__ Wth,
                                                   unsigned short* __restrict__ Wtl,
                                                   int Kdim, int Ndim)
{
    __shared__ float T[64][65];
    int n0 = blockIdx.x * 64, k0 = blockIdx.y * 64;
    int tid = threadIdx.x;
    int rr = tid >> 4, cc = (tid & 15) * 4;
#pragma unroll
    for (int p = 0; p < 4; ++p) {
        int r = rr + p * 16;
        float4 x = *(const float4*)&W[(size_t)(k0 + r) * Ndim + n0 + cc];
        T[r][cc] = x.x; T[r][cc + 1] = x.y; T[r][cc + 2] = x.z; T[r][cc + 3] = x.w;
    }
    __syncthreads();
#pragma unroll
    for (int p = 0; p < 4; ++p) {
        int rn = rr + p * 16;
        float v0 = T[cc][rn], v1 = T[cc + 1][rn], v2 = T[cc + 2][rn], v3 = T[cc + 3][rn];
        ushort4 h, l;
        h.x = f2b(v0); l.x = f2b(v0 - b2f(h.x));
        h.y = f2b(v1); l.y = f2b(v1 - b2f(h.y));
        h.z = f2b(v2); l.z = f2b(v2 - b2f(h.z));
        h.w = f2b(v3); l.w = f2b(v3 - b2f(h.w));
        *(ushort4*)&Wth[(size_t)(n0 + rn) * Kdim + k0 + cc] = h;
        *(ushort4*)&Wtl[(size_t)(n0 + rn) * Kdim + k0 + cc] = l;
    }
}

// ---------------------------------------------------------------------------
// Single-bf16 MFMA GEMM: C = A @ Bt^T. 128x128 tile, 4 waves, 4x4 frags.
// Staging via global_load_lds (LDS layout is tid-linear *16B).
// MODE 0: C[m*N+n].  MODE 1: qkv permute -> C[((b*NH+h)*S+s)*HD+d].
// ---------------------------------------------------------------------------
template<int MODE>
__global__ __launch_bounds__(256) void gemm_bf16t(const unsigned short* __restrict__ A,
                                                  const unsigned short* __restrict__ Bt,
                                                  float* __restrict__ C,
                                                  int M, int N, int K)
{
    __shared__ unsigned short As[128 * 32];
    __shared__ unsigned short Bs[128 * 32];
    const int tid = threadIdx.x;
    const int bm = blockIdx.y * 128, bn = blockIdx.x * 128;
    const int lane = tid & 63, wid = tid >> 6;
    const int wr = (wid >> 1) * 64, wc = (wid & 1) * 64;
    const int lm = lane & 15, lk = (lane >> 4) * 8;

    f32x4 acc[4][4];
#pragma unroll
    for (int mi = 0; mi < 4; ++mi)
#pragma unroll
        for (int ni = 0; ni < 4; ++ni) acc[mi][ni] = 0.0f;

    for (int k0 = 0; k0 < K; k0 += 32) {
#pragma unroll
        for (int l = 0; l < 2; ++l) {
            int L = tid + l * 256;
            int row = L >> 2, c8 = (L & 3) * 8;
            gload16(&A[(size_t)(bm + row) * K + k0 + c8], &As[L * 8]);
            gload16(&Bt[(size_t)(bn + row) * K + k0 + c8], &Bs[L * 8]);
        }
        __syncthreads();
        short8 af[4], bf[4];
#pragma unroll
        for (int mi = 0; mi < 4; ++mi) af[mi] = *(short8*)&As[(wr + mi * 16 + lm) * 32 + lk];
#pragma unroll
        for (int ni = 0; ni < 4; ++ni) bf[ni] = *(short8*)&Bs[(wc + ni * 16 + lm) * 32 + lk];
#pragma unroll
        for (int mi = 0; mi < 4; ++mi)
#pragma unroll
            for (int ni = 0; ni < 4; ++ni)
                acc[mi][ni] = __builtin_amdgcn_mfma_f32_16x16x32_bf16(af[mi], bf[ni], acc[mi][ni], 0, 0, 0);
        __syncthreads();
    }
    const int lr = (lane >> 4) * 4;  // C/D: col=lane&15, row=(lane>>4)*4+reg
#pragma unroll
    for (int mi = 0; mi < 4; ++mi)
#pragma unroll
        for (int ni = 0; ni < 4; ++ni)
#pragma unroll
            for (int r = 0; r < 4; ++r) {
                int m = bm + wr + mi * 16 + lr + r;
                int n = bn + wc + ni * 16 + lm;
                float vv = acc[mi][ni][r];
                if (MODE == 0) {
                    C[(size_t)m * N + n] = vv;
                } else {
                    int b_ = m / Ss, s_ = m % Ss;
                    int h_ = n / HDd, d_ = n % HDd;
                    C[(size_t)((b_ * NHh + h_) * Ss + s_) * HDd + d_] = vv;
                }
            }
}

// ---------------------------------------------------------------------------
// Split-bf16 MFMA GEMM (hi/lo): C = (Ah+Al) @ (Bh+Bl)^T, dropping Al*Bl.
// 3 MFMAs per fragment pair. Staging via global_load_lds.
// ---------------------------------------------------------------------------
template<int MODE>
__global__ __launch_bounds__(256) void gemm_split(const unsigned short* __restrict__ Ah,
                                                  const unsigned short* __restrict__ Al,
                                                  const unsigned short* __restrict__ Bh,
                                                  const unsigned short* __restrict__ Bl,
                                                  float* __restrict__ C,
                                                  int M, int N, int K)
{
    __shared__ unsigned short AsH[128 * 32], AsL[128 * 32];
    __shared__ unsigned short BsH[128 * 32], BsL[128 * 32];
    const int tid = threadIdx.x;
    const int bm = blockIdx.y * 128, bn = blockIdx.x * 128;
    const int lane = tid & 63, wid = tid >> 6;
    const int wr = (wid >> 1) * 64, wc = (wid & 1) * 64;
    const int lm = lane & 15, lk = (lane >> 4) * 8;

    f32x4 acc[4][4];
#pragma unroll
    for (int mi = 0; mi < 4; ++mi)
#pragma unroll
        for (int ni = 0; ni < 4; ++ni) acc[mi][ni] = 0.0f;

    for (int k0 = 0; k0 < K; k0 += 32) {
#pragma unroll
        for (int l = 0; l < 2; ++l) {
            int L = tid + l * 256;
            int row = L >> 2, c8 = (L & 3) * 8;
            size_t ga = (size_t)(bm + row) * K + k0 + c8;
            size_t gb = (size_t)(bn + row) * K + k0 + c8;
            gload16(&Ah[ga], &AsH[L * 8]);
            gload16(&Al[ga], &AsL[L * 8]);
            gload16(&Bh[gb], &BsH[L * 8]);
            gload16(&Bl[gb], &BsL[L * 8]);
        }
        __syncthreads();
        short8 ah[4], al[4], bh[4], bl[4];
#pragma unroll
        for (int mi = 0; mi < 4; ++mi) {
            ah[mi] = *(short8*)&AsH[(wr + mi * 16 + lm) * 32 + lk];
            al[mi] = *(short8*)&AsL[(wr + mi * 16 + lm) * 32 + lk];
        }
#pragma unroll
        for (int ni = 0; ni < 4; ++ni) {
            bh[ni] = *(short8*)&BsH[(wc + ni * 16 + lm) * 32 + lk];
            bl[ni] = *(short8*)&BsL[(wc + ni * 16 + lm) * 32 + lk];
        }
#pragma unroll
        for (int mi = 0; mi < 4; ++mi)
#pragma unroll
            for (int ni = 0; ni < 4; ++ni) {
                acc[mi][ni] = __builtin_amdgcn_mfma_f32_16x16x32_bf16(ah[mi], bh[ni], acc[mi][ni], 0, 0, 0);
                acc[mi][ni] = __builtin_amdgcn_mfma_f32_16x16x32_bf16(ah[mi], bl[ni], acc[mi][ni], 0, 0, 0);
                acc[mi][ni] = __builtin_amdgcn_mfma_f32_16x16x32_bf16(al[mi], bh[ni], acc[mi][ni], 0, 0, 0);
            }
        __syncthreads();
    }
    const int lr = (lane >> 4) * 4;
#pragma unroll
    for (int mi = 0; mi < 4; ++mi)
#pragma unroll
        for (int ni = 0; ni < 4; ++ni)
#pragma unroll
            for (int r = 0; r < 4; ++r) {
                int m = bm + wr + mi * 16 + lr + r;
                int n = bn + wc + ni * 16 + lm;
                float vv = acc[mi][ni][r];
                if (MODE == 0) {
                    C[(size_t)m * N + n] = vv;
                } else {
                    int b_ = m / Ss, s_ = m % Ss;
                    int h_ = n / HDd, d_ = n % HDd;
                    C[(size_t)((b_ * NHh + h_) * Ss + s_) * HDd + d_] = vv;
                }
            }
}

// ---------------------------------------------------------------------------
// RoPE (fp32 math) -> split bf16 q,k (hi/lo).
// ---------------------------------------------------------------------------
__global__ __launch_bounds__(64) void rope_qk_split(const float* __restrict__ q,
                                                    const float* __restrict__ k,
                                                    unsigned short* __restrict__ qh,
                                                    unsigned short* __restrict__ ql,
                                                    unsigned short* __restrict__ kh,
                                                    unsigned short* __restrict__ kl)
{
    int idx = blockIdx.x;          // bh*S + s
    int s = idx % Ss;
    int d = threadIdx.x;           // 0..63
    float inv = powf(10000.0f, -2.0f * (float)d / 128.0f);
    float fr = (float)s * inv;
    float c = cosf(fr), sn = sinf(fr);
    size_t base = (size_t)idx * HDd;
    float q1 = q[base + d], q2 = q[base + d + 64];
    float k1 = k[base + d], k2 = k[base + d + 64];
    float qa = q1 * c - q2 * sn, qbv = q2 * c + q1 * sn;
    float ka = k1 * c - k2 * sn, kbv = k2 * c + k1 * sn;
    unsigned short h;
    h = f2b(qa);  qh[base + d]      = h; ql[base + d]      = f2b(qa  - b2f(h));
    h = f2b(qbv); qh[base + d + 64] = h; ql[base + d + 64] = f2b(qbv - b2f(h));
    h = f2b(ka);  kh[base + d]      = h; kl[base + d]      = f2b(ka  - b2f(h));
    h = f2b(kbv); kh[base + d + 64] = h; kl[base + d + 64] = f2b(kbv - b2f(h));
}

// ---------------------------------------------------------------------------
// attn = q k^T / sqrt(HD) via split-bf16 MFMA, causal mask to MASKVAL.
// ---------------------------------------------------------------------------
__global__ __launch_bounds__(256) void attn_qk_split(const unsigned short* __restrict__ qh,
                                                     const unsigned short* __restrict__ ql,
                                                     const unsigned short* __restrict__ kh,
                                                     const unsigned short* __restrict__ kl,
                                                     float* __restrict__ attn)
{
    const int bh = blockIdx.z;
    const int bm = blockIdx.y * 128, bn = blockIdx.x * 128;
    float* C = attn + (size_t)bh * Ss * Ss;
    const int tid = threadIdx.x;

    if (blockIdx.x > blockIdx.y) {  // fully above diagonal
        float4 mv = make_float4(MASKVAL, MASKVAL, MASKVAL, MASKVAL);
#pragma unroll
        for (int i = 0; i < 16; ++i) {
            int L = tid + i * 256;
            int row = L >> 5, c4 = (L & 31) * 4;
            *(float4*)&C[(size_t)(bm + row) * Ss + bn + c4] = mv;
        }
        return;
    }
    const size_t hb = (size_t)bh * Ss * HDd;
    const unsigned short* Ah = qh + hb;
    const unsigned short* Al = ql + hb;
    const unsigned short* Bh = kh + hb;
    const unsigned short* Bl = kl + hb;

    __shared__ unsigned short AsH[128 * 32], AsL[128 * 32];
    __shared__ unsigned short BsH[128 * 32], BsL[128 * 32];
    const int lane = tid & 63, wid = tid >> 6;
    const int wr = (wid >> 1) * 64, wc = (wid & 1) * 64;
    const int lm = lane & 15, lk = (lane >> 4) * 8;

    f32x4 acc[4][4];
#pragma unroll
    for (int mi = 0; mi < 4; ++mi)
#pragma unroll
        for (int ni = 0; ni < 4; ++ni) acc[mi][ni] = 0.0f;

    for (int k0 = 0; k0 < HDd; k0 += 32) {
#pragma unroll
        for (int l = 0; l < 2; ++l) {
            int L = tid + l * 256;
            int row = L >> 2, c8 = (L & 3) * 8;
            size_t ga = (size_t)(bm + row) * HDd + k0 + c8;
            size_t gb = (size_t)(bn + row) * HDd + k0 + c8;
            gload16(&Ah[ga], &AsH[L * 8]);
            gload16(&Al[ga], &AsL[L * 8]);
            gload16(&Bh[gb], &BsH[L * 8]);
            gload16(&Bl[gb], &BsL[L * 8]);
        }
        __syncthreads();
        short8 ah[4], al[4], bh2[4], bl2[4];
#pragma unroll
        for (int mi = 0; mi < 4; ++mi) {
            ah[mi] = *(short8*)&AsH[(wr + mi * 16 + lm) * 32 + lk];
            al[mi] = *(short8*)&AsL[(wr + mi * 16 + lm) * 32 + lk];
        }
#pragma unroll
        for (int ni = 0; ni < 4; ++ni) {
            bh2[ni] = *(short8*)&BsH[(wc + ni * 16 + lm) * 32 + lk];
            bl2[ni] = *(short8*)&BsL[(wc + ni * 16 + lm) * 32 + lk];
        }
#pragma unroll
        for (int mi = 0; mi < 4; ++mi)
#pragma unroll
            for (int ni = 0; ni < 4; ++ni) {
                acc[mi][ni] = __builtin_amdgcn_mfma_f32_16x16x32_bf16(ah[mi], bh2[ni], acc[mi][ni], 0, 0, 0);
                acc[mi][ni] = __builtin_amdgcn_mfma_f32_16x16x32_bf16(ah[mi], bl2[ni], acc[mi][ni], 0, 0, 0);
                acc[mi][ni] = __builtin_amdgcn_mfma_f32_16x16x32_bf16(al[mi], bh2[ni], acc[mi][ni], 0, 0, 0);
            }
        __syncthreads();
    }
    const float scale = 0.08838834764831845f;  // 1/sqrt(128)
    const int lr = (lane >> 4) * 4;
#pragma unroll
    for (int mi = 0; mi < 4; ++mi)
#pragma unroll
        for (int ni = 0; ni < 4; ++ni)
#pragma unroll
            for (int r = 0; r < 4; ++r) {
                int sq = bm + wr + mi * 16 + lr + r;
                int sk = bn + wc + ni * 16 + lm;
                C[(size_t)sq * Ss + sk] = (sk <= sq) ? acc[mi][ni][r] * scale : MASKVAL;
            }
}

// ---------------------------------------------------------------------------
// Row softmax IN PLACE: attn -> scores = exp(a - rowmax) / rowsum.
// ---------------------------------------------------------------------------
__global__ __launch_bounds__(256) void softmax_rows(float* __restrict__ attn)
{
    int row = blockIdx.x;
    float4* a4 = (float4*)(attn + (size_t)row * Ss);
    int tid = threadIdx.x;
    float4 x = a4[tid];
    float m = fmaxf(fmaxf(x.x, x.y), fmaxf(x.z, x.w));
#pragma unroll
    for (int off = 32; off; off >>= 1) m = fmaxf(m, __shfl_xor(m, off));
    __shared__ float red[4];
    if ((tid & 63) == 0) red[tid >> 6] = m;
    __syncthreads();
    float mm = fmaxf(fmaxf(red[0], red[1]), fmaxf(red[2], red[3]));
    float e0 = expf(x.x - mm), e1 = expf(x.y - mm);
    float e2 = expf(x.z - mm), e3 = expf(x.w - mm);
    float s = e0 + e1 + e2 + e3;
#pragma unroll
    for (int off = 32; off; off >>= 1) s += __shfl_xor(s, off);
    __shared__ float red2[4];
    if ((tid & 63) == 0) red2[tid >> 6] = s;
    __syncthreads();
    float inv = 1.0f / (red2[0] + red2[1] + red2[2] + red2[3]);
    a4[tid] = make_float4(e0 * inv, e1 * inv, e2 * inv, e3 * inv);
}

// ---------------------------------------------------------------------------
// DPP cross-lane helpers (VALU-latency, no LDS pipe).
// ---------------------------------------------------------------------------
template<int CTRL>
__device__ __forceinline__ int dpp_i(int x) {
    return __builtin_amdgcn_update_dpp(0, x, CTRL, 0xF, 0xF, true);
}
__device__ __forceinline__ float wave_sum64(float x) {
    x += __int_as_float(dpp_i<0xB1>(__float_as_int(x)));
    x += __int_as_float(dpp_i<0x4E>(__float_as_int(x)));
    x += __int_as_float(dpp_i<0x141>(__float_as_int(x)));
    x += __int_as_float(dpp_i<0x140>(__float_as_int(x)));
    int xi = __float_as_int(x);
    float a = __int_as_float(__builtin_amdgcn_readlane(xi, 0));
    float b = __int_as_float(__builtin_amdgcn_readlane(xi, 16));
    float c = __int_as_float(__builtin_amdgcn_readlane(xi, 32));
    float d = __int_as_float(__builtin_amdgcn_readlane(xi, 48));
    return (a + c) + (b + d);
}

// 64-bit packed-key (value<<32 | index) helpers: lexicographic min == exact
// float-min with first-index tie-break (values are non-negative floats).
__device__ __forceinline__ unsigned long long u64min(unsigned long long a, unsigned long long b) {
    return a < b ? a : b;
}
template<int CTRL>
__device__ __forceinline__ unsigned long long dpp64(unsigned long long x) {
    int lo = (int)(unsigned)x;
    int hi = (int)(unsigned)(x >> 32);
    unsigned l2 = (unsigned)dpp_i<CTRL>(lo);
    unsigned h2 = (unsigned)dpp_i<CTRL>(hi);
    return ((unsigned long long)h2 << 32) | (unsigned long long)l2;
}
__device__ __forceinline__ unsigned long long wave_min64k(unsigned long long x) {
    x = u64min(x, dpp64<0xB1>(x));
    x = u64min(x, dpp64<0x4E>(x));
    x = u64min(x, dpp64<0x141>(x));
    x = u64min(x, dpp64<0x140>(x));
    int lo = (int)(unsigned)x;
    int hi = (int)(unsigned)(x >> 32);
    unsigned long long a = ((unsigned long long)(unsigned)__builtin_amdgcn_readlane(hi, 0)  << 32) |
                           (unsigned long long)(unsigned)__builtin_amdgcn_readlane(lo, 0);
    unsigned long long b = ((unsigned long long)(unsigned)__builtin_amdgcn_readlane(hi, 16) << 32) |
                           (unsigned long long)(unsigned)__builtin_amdgcn_readlane(lo, 16);
    unsigned long long c = ((unsigned long long)(unsigned)__builtin_amdgcn_readlane(hi, 32) << 32) |
                           (unsigned long long)(unsigned)__builtin_amdgcn_readlane(lo, 32);
    unsigned long long d = ((unsigned long long)(unsigned)__builtin_amdgcn_readlane(hi, 48) << 32) |
                           (unsigned long long)(unsigned)__builtin_amdgcn_readlane(lo, 48);
    return u64min(u64min(a, b), u64min(c, d));
}

// ---------------------------------------------------------------------------
// A2S sequential scan v8 = v5 skeleton (single wave, branchless) +
//  - packed fp32 (f32x2) elementwise math -> v_pk_mul/v_pk_fma halve the
//    per-element issue count (cur*inv and sel fma are single-rounded,
//    identical to scalar fmaf);
//  - compile-time LM (min lead) phases: chunks jj<LM are provably fully
//    inside the eviction window for the whole phase -> key = raw sel bits
//    (chunk 0 keeps the precomputed ge select), no per-element s<=local
//    compare. Chunks jj>=LM do the full windowed compare (always correct).
//    All control flow template-resolved (R2 lesson: no runtime branches).
// ---------------------------------------------------------------------------
template<int NC, int NCL, int LM>
__device__ __forceinline__ void scan_step8(int t, int lane,
                                           const float4* __restrict__ A4,
                                           unsigned char* __restrict__ KP,
                                           float4 (&rb)[4],
                                           f32x2 (&sel)[4][2],
                                           f32x2 (&mf)[4][2],
                                           bool ge)
{
    const float INFv = __int_as_float(0x7f800000);
    // snapshot row t
    float4 a[NC];
#pragma unroll
    for (int jj = 0; jj < NC; ++jj) a[jj] = rb[jj];
    // prefetch row t+4 (clamped), NCL chunks
    int tp = t + 4; if (tp > Ss - 1) tp = Ss - 1;
#pragma unroll
    for (int jj = 0; jj < NCL; ++jj) rb[jj] = A4[tp * 256 + jj * 64 + lane];

    // masked row sum (packed) — pairing (c0+c2)+(c1+c3); tot-level rounding
    // differences have been absorbed by decision margins across v4/v5/v7.
    f32x2 acc2; acc2.x = 0.0f; acc2.y = 0.0f;
#pragma unroll
    for (int jj = 0; jj < NC; ++jj) {
        f32x2 a01; a01.x = a[jj].x; a01.y = a[jj].y;
        f32x2 a23; a23.x = a[jj].z; a23.y = a[jj].w;
        acc2 += a01 * mf[jj][0] + a23 * mf[jj][1];
    }
    float lsum = acc2.x + acc2.y;
    float tot = wave_sum64(lsum);
    float inv = 1.0f / tot;
    f32x2 inv2; inv2.x = inv; inv2.y = inv;
    f32x2 ff2;  ff2.x = FFf;  ff2.y = FFf;

    const int local = t - RBc;
    const int base4 = lane * 4;

    // sel update (packed pk_fma) + windowed argmin via packed (val,idx) keys
    unsigned long long kmin = 0xFFFFFFFFFFFFFFFFull;
#pragma unroll
    for (int jj = 0; jj < NC; ++jj) {
        f32x2 a01; a01.x = a[jj].x; a01.y = a[jj].y;
        f32x2 a23; a23.x = a[jj].z; a23.y = a[jj].w;
        f32x2 cur01 = a01 * inv2;            // pk_mul, same rounding as scalar
        f32x2 cur23 = a23 * inv2;
        f32x2 s01 = sel[jj][0] * ff2 + cur01; // contracts to pk_fma == fmaf
        f32x2 s23 = sel[jj][1] * ff2 + cur23;
        sel[jj][0] = s01;
        sel[jj][1] = s23;
        float sv[4]; sv[0] = s01.x; sv[1] = s01.y; sv[2] = s23.x; sv[3] = s23.y;
        unsigned long long kk[4];
#pragma unroll
        for (int i = 0; i < 4; ++i) {
            int s = jj * 256 + base4 + i;
            unsigned hi;
            if (jj < LM) {
                // fully inside window for entire phase (no s<=local compare)
                if (jj == 0) hi = ge ? __float_as_uint(sv[i]) : 0x7f800000u;
                else         hi = __float_as_uint(sv[i]);
            } else {
                bool win = (s <= local) && (jj > 0 || ge);
                hi = win ? __float_as_uint(sv[i]) : 0x7f800000u;
            }
            kk[i] = ((unsigned long long)hi << 32) | (unsigned long long)(unsigned)s;
        }
        kmin = u64min(kmin, u64min(u64min(kk[0], kk[1]), u64min(kk[2], kk[3])));
    }
    kmin = wave_min64k(kmin);
    const int besti = (int)(unsigned)(kmin & 0xFFFFFFFFull);

    // evict (branchless vector compare, v5 style)
#pragma unroll
    for (int jj = 0; jj < NC; ++jj) {
        int s0 = jj * 256 + base4;
        bool e0 = (s0 + 0 == besti);
        bool e1 = (s0 + 1 == besti);
        bool e2 = (s0 + 2 == besti);
        bool e3 = (s0 + 3 == besti);
        sel[jj][0].x = e0 ? INFv : sel[jj][0].x;
        sel[jj][0].y = e1 ? INFv : sel[jj][0].y;
        sel[jj][1].x = e2 ? INFv : sel[jj][1].x;
        sel[jj][1].y = e3 ? INFv : sel[jj][1].y;
        mf[jj][0].x = e0 ? 0.0f : mf[jj][0].x;
        mf[jj][0].y = e1 ? 0.0f : mf[jj][0].y;
        mf[jj][1].x = e2 ? 0.0f : mf[jj][1].x;
        mf[jj][1].y = e3 ? 0.0f : mf[jj][1].y;
    }

    // keep row t+1 (chunks 0..NC-1; scores are exactly 0 above, don't-care)
    uchar4* kp4 = (uchar4*)(KP + (size_t)(t + 1) * Ss);
#pragma unroll
    for (int jj = 0; jj < NC; ++jj) {
        uchar4 kb;
        kb.x = (unsigned char)mf[jj][0].x;
        kb.y = (unsigned char)mf[jj][0].y;
        kb.z = (unsigned char)mf[jj][1].x;
        kb.w = (unsigned char)mf[jj][1].y;
        kp4[jj * 64 + lane] = kb;
    }
}

#define SCAN_PHASE(BEG, END, NC, NCL, LM)                                    \
    for (int t0 = (BEG); t0 < (END); t0 += 4) {                              \
        scan_step8<NC, NCL, LM>(t0 + 0, lane, A4, KP, rb[0], sel, mf, ge);   \
        scan_step8<NC, NCL, LM>(t0 + 1, lane, A4, KP, rb[1], sel, mf, ge);   \
        scan_step8<NC, NCL, LM>(t0 + 2, lane, A4, KP, rb[2], sel, mf, ge);   \
        scan_step8<NC, NCL, LM>(t0 + 3, lane, A4, KP, rb[3], sel, mf, ge);   \
    }

__global__ __launch_bounds__(64) void scan_kernel8(const float* __restrict__ scores,
                                                   unsigned char* __restrict__ keep)
{
    int bh = blockIdx.x;
    int lane = threadIdx.x;
    const float4* A4 = (const float4*)(scores + (size_t)bh * Ss * Ss);
    unsigned char* KP = keep + (size_t)bh * Ss * Ss;

    f32x2 sel[4][2];
    f32x2 mf[4][2];
#pragma unroll
    for (int jj = 0; jj < 4; ++jj)
#pragma unroll
        for (int p = 0; p < 2; ++p) {
            sel[jj][p].x = 0.0f; sel[jj][p].y = 0.0f;
            mf[jj][p].x = 1.0f;  mf[jj][p].y = 1.0f;
        }
    const bool ge = (lane * 4 >= SBc);

    // ---- warmup rows 0..162: chunk 0 only (rows <163 are zero beyond col 162)
    float4 w0 = A4[0 * 256 + lane];
    float4 w1 = A4[1 * 256 + lane];
    float4 w2 = A4[2 * 256 + lane];
    float4 w3 = A4[3 * 256 + lane];
    f32x2 ff2; ff2.x = FFf; ff2.y = FFf;
#define WSTEP(W, NEXT)                                                       \
    do {                                                                     \
        float4 _a = W;                                                       \
        W = A4[(NEXT) * 256 + lane];                                         \
        f32x2 a01; a01.x = _a.x; a01.y = _a.y;                               \
        f32x2 a23; a23.x = _a.z; a23.y = _a.w;                               \
        sel[0][0] = sel[0][0] * ff2 + a01;                                   \
        sel[0][1] = sel[0][1] * ff2 + a23;                                   \
    } while (0)
    for (int r = 0; r < 160; r += 4) {
        WSTEP(w0, r + 4); WSTEP(w1, r + 5); WSTEP(w2, r + 6); WSTEP(w3, r + 7);
    }
#undef WSTEP
    {   // rows 160..162 tail (w3 = row 163 discarded)
        float4 tl[3] = { w0, w1, w2 };
#pragma unroll
        for (int u = 0; u < 3; ++u) {
            f32x2 a01; a01.x = tl[u].x; a01.y = tl[u].y;
            f32x2 a23; a23.x = tl[u].z; a23.y = tl[u].w;
            sel[0][0] = sel[0][0] * ff2 + a01;
            sel[0][1] = sel[0][1] * ff2 + a23;
        }
    }

    // ---- init scan prefetch: rows 163..166, chunk 0 ----
    float4 rb[4][4];
#pragma unroll
    for (int slot = 0; slot < 4; ++slot)
        rb[slot][0] = A4[(163 + slot) * 256 + lane];

    // ---- phased scan: t = 163..1022 (keep rows 164..1023) ----
    // lead(t) = (t-82)>>8 increments at t = 338, 594, 850; phases split on
    // 4-aligned boundaries with LM = min lead over the phase.
    SCAN_PHASE(163, 255, 1, 2, 0)
    SCAN_PHASE(255, 339, 2, 3, 0)
    SCAN_PHASE(339, 511, 2, 3, 1)
    SCAN_PHASE(511, 595, 3, 4, 1)
    SCAN_PHASE(595, 767, 3, 4, 2)
    SCAN_PHASE(767, 851, 4, 4, 2)
    SCAN_PHASE(851, 1023, 4, 4, 3)
}
#undef SCAN_PHASE

// ---------------------------------------------------------------------------
// Fused mask + renorm + PV: ctx = (keep.*P) @ V / rowsum(keep.*P).
// ---------------------------------------------------------------------------
__global__ __launch_bounds__(256) void pv_renorm(const float* __restrict__ scores,
                                                 const unsigned char* __restrict__ keep,
                                                 const float* __restrict__ v,
                                                 unsigned short* __restrict__ ctxb)
{
    int bh = blockIdx.z;
    int b_ = bh / NHh, h_ = bh % NHh;
    const float* P = scores + (size_t)bh * Ss * Ss;
    const unsigned char* KPm = keep + (size_t)bh * Ss * Ss;
    const float* V = v + (size_t)bh * Ss * HDd;
    int bm = blockIdx.y * 64, bn = blockIdx.x * 64;
    int tid = threadIdx.x, tx = tid & 15, ty = tid >> 4;
    __shared__ float As[16][65];
    __shared__ float Bs[16][64];
    float acc[4][4] = {};
    float rs[4] = {};
    int kend = bm + 64;  // causal truncation (covers full causal row extent)
    for (int k0 = 0; k0 < kend; k0 += 16) {
#pragma unroll
        for (int l = 0; l < 4; ++l) {
            int idx = tid + l * 256;
            int r = idx >> 4, c = idx & 15;
            int row = bm + r;
            float p = P[(size_t)row * Ss + k0 + c];
            if (row > CBc && !KPm[(size_t)row * Ss + k0 + c]) p = 0.0f;
            As[c][r] = p;
        }
#pragma unroll
        for (int l = 0; l < 4; ++l) {
            int idx = tid + l * 256;
            int r = idx >> 6, c = idx & 63;
            Bs[r][c] = V[(size_t)(k0 + r) * HDd + bn + c];
        }
        __syncthreads();
#pragma unroll
        for (int kk = 0; kk < 16; ++kk) {
            float a[4], b[4];
#pragma unroll
            for (int i = 0; i < 4; ++i) a[i] = As[kk][ty * 4 + i];
#pragma unroll
            for (int j = 0; j < 4; ++j) b[j] = Bs[kk][tx * 4 + j];
#pragma unroll
            for (int i = 0; i < 4; ++i) rs[i] += a[i];
#pragma unroll
            for (int i = 0; i < 4; ++i)
#pragma unroll
                for (int j = 0; j < 4; ++j)
                    acc[i][j] = fmaf(a[i], b[j], acc[i][j]);
        }
        __syncthreads();
    }
#pragma unroll
    for (int i = 0; i < 4; ++i) {
        float inv = 1.0f / rs[i];   // rs > 0 (diagonal prob always kept)
        int sq = bm + ty * 4 + i;
#pragma unroll
        for (int j = 0; j < 4; ++j) {
            int d = bn + tx * 4 + j;
            ctxb[(size_t)(b_ * Ss + sq) * HIDd + h_ * HDd + d] = f2b(acc[i][j] * inv);
        }
    }
}

// ---------------------------------------------------------------------------
extern "C" void kernel_launch(void* const* d_in, const int* in_sizes, int n_in,
                              void* d_out, int out_size, void* d_ws, size_t ws_size,
                              hipStream_t stream)
{
    const float* hs = (const float*)d_in[0];
    const float* wq = (const float*)d_in[1];
    const float* wk = (const float*)d_in[2];
    const float* wv = (const float*)d_in[3];
    const float* wo = (const float*)d_in[4];
    float* out = (float*)d_out;

    float* ws = (float*)d_ws;
    size_t off = 0;
    float* qf   = ws + off; off += (size_t)NBH * Ss * HDd;   // 16 MB (reused: ctxb)
    float* kf   = ws + off; off += (size_t)NBH * Ss * HDd;   // 16 MB
    float* vf   = ws + off; off += (size_t)NBH * Ss * HDd;   // 16 MB
    float* attn = ws + off; off += (size_t)NBH * Ss * Ss;    // 128 MB
    unsigned char* keep = (unsigned char*)(ws + off); off += (size_t)NBH * Ss * Ss / 4; // 32 MB
    unsigned short* wot = (unsigned short*)(ws + off); off += (size_t)HIDd * HIDd / 2;  // 8 MB

    // Transients overlaid on attn (dead before attn is written). 8 MB = 2M floats each.
    unsigned short* hsh  = (unsigned short*)(attn);
    unsigned short* hsl  = (unsigned short*)(attn + 2u * 1024 * 1024);
    unsigned short* wqth = (unsigned short*)(attn + 4u * 1024 * 1024);
    unsigned short* wqtl = (unsigned short*)(attn + 6u * 1024 * 1024);
    unsigned short* wkth = (unsigned short*)(attn + 8u * 1024 * 1024);
    unsigned short* wktl = (unsigned short*)(attn + 10u * 1024 * 1024);
    unsigned short* wvt  = (unsigned short*)(attn + 12u * 1024 * 1024);
    // q/k split bf16 overlaid on keep (keep written only by the scan, later):
    unsigned short* qh = (unsigned short*)keep;
    unsigned short* ql = (unsigned short*)(keep + 8u * 1024 * 1024);
    unsigned short* kh = (unsigned short*)(keep + 16u * 1024 * 1024);
    unsigned short* kl = (unsigned short*)(keep + 24u * 1024 * 1024);
    // ctxb overlays qf (qf dead after rope):
    unsigned short* ctxb = (unsigned short*)qf;

    dim3 blk(256);
    const int M = Bb * Ss;  // 2048

    // hs -> split bf16
    conv_split<<<dim3((M * HIDd / 4 + 255) / 256), blk, 0, stream>>>(hs, hsh, hsl, M * HIDd / 4);

    // weight transposes
    dim3 gt(HIDd / 64, HIDd / 64);
    tconv_split<<<gt, blk, 0, stream>>>(wq, wqth, wqtl, HIDd, HIDd);
    tconv_split<<<gt, blk, 0, stream>>>(wk, wkth, wktl, HIDd, HIDd);
    tconv<<<gt, blk, 0, stream>>>(wv, wvt, HIDd, HIDd);
    tconv<<<gt, blk, 0, stream>>>(wo, wot, HIDd, HIDd);

    // projections: q,k split-precision MFMA; v single bf16 MFMA
    dim3 gp(HIDd / 128, M / 128);   // 16 x 16
    gemm_split<1><<<gp, blk, 0, stream>>>(hsh, hsl, wqth, wqtl, qf, M, HIDd, HIDd);
    gemm_split<1><<<gp, blk, 0, stream>>>(hsh, hsl, wkth, wktl, kf, M, HIDd, HIDd);
    gemm_bf16t<1><<<gp, blk, 0, stream>>>(hsh, wvt, vf, M, HIDd, HIDd);

    // RoPE (fp32 math) -> split bf16 q,k
    rope_qk_split<<<dim3(NBH * Ss), dim3(64), 0, stream>>>(qf, kf, qh, ql, kh, kl);

    // QK^T (split-precision MFMA) + causal mask
    attn_qk_split<<<dim3(Ss / 128, Ss / 128, NBH), blk, 0, stream>>>(qh, ql, kh, kl, attn);

    // attn -> normalized scores, in place
    softmax_rows<<<dim3(NROWS), blk, 0, stream>>>(attn);

    // sequential A2S scan (v5 skeleton + packed math + LM phases) -> keep
    scan_kernel8<<<dim3(NBH), dim3(64), 0, stream>>>(attn, keep);

    // fused mask + renorm + PV (fp32 math, bf16 out)
    pv_renorm<<<dim3(HDd / 64, Ss / 64, NBH), blk, 0, stream>>>(attn, keep, vf, ctxb);

    // out = ctx @ wo (bf16 MFMA, fp32 out)
    gemm_bf16t<0><<<gp, blk, 0, stream>>>(ctxb, wot, out, M, HIDd, HIDd);
}

// Round 5
// 985.854 us; speedup vs baseline: 1.2083x; 1.0685x over previous
//
#include <hip/hip_runtime.h>
#include <math.h>

// Problem constants (from reference)
#define Bb    2
#define Ss    1024
#define HIDd  2048
#define NHh   16
#define HDd   128
#define SBc   20      // floor(0.02*1024+0.5)
#define SELBc 61      // floor(0.06*1024+0.5)
#define RBc   82      // floor(0.08*1024+0.5)
#define CBc   163     // SB+SELB+RB
#define FFf   0.9f
#define MASKVAL (-3.4028234663852886e38f)
#define NBH   (Bb*NHh)       // 32
#define NROWS (NBH*Ss)       // 32768

typedef __attribute__((ext_vector_type(8))) short short8;
typedef __attribute__((ext_vector_type(4))) float f32x4;

__device__ __forceinline__ unsigned short f2b(float f) {
    unsigned u = __float_as_uint(f);
    u = (u + 0x7FFFu + ((u >> 16) & 1u)) >> 16;   // RNE
    return (unsigned short)u;
}
__device__ __forceinline__ float b2f(unsigned short h) {
    return __uint_as_float((unsigned)h << 16);
}

// ---------------------------------------------------------------------------
// Async global->LDS direct DMA (16B/lane). LDS dest = wave-uniform base +
// lane*16 (hardware rule); all call sites below have tid-linear LDS layouts.
// ---------------------------------------------------------------------------
#if defined(__has_builtin)
#if __has_builtin(__builtin_amdgcn_global_load_lds)
#define USE_GLD 1
#endif
#endif

__device__ __forceinline__ void gload16(const void* g, void* l) {
#ifdef USE_GLD
    __builtin_amdgcn_global_load_lds(
        (const __attribute__((address_space(1))) void*)g,
        (__attribute__((address_space(3))) void*)l, 16, 0, 0);
#else
    *(short8*)l = *(const short8*)g;
#endif
}

// ---------------------------------------------------------------------------
// fp32 -> split bf16 (hi + lo). lo = bf16(x - fp32(hi)).
// ---------------------------------------------------------------------------
__global__ __launch_bounds__(256) void conv_split(const float* __restrict__ x,
                                                  unsigned short* __restrict__ yh,
                                                  unsigned short* __restrict__ yl, int n4)
{
    int i = blockIdx.x * 256 + threadIdx.x;
    if (i >= n4) return;
    float4 v = ((const float4*)x)[i];
    ushort4 h, l;
    h.x = f2b(v.x); l.x = f2b(v.x - b2f(h.x));
    h.y = f2b(v.y); l.y = f2b(v.y - b2f(h.y));
    h.z = f2b(v.z); l.z = f2b(v.z - b2f(h.z));
    h.w = f2b(v.w); l.w = f2b(v.w - b2f(h.w));
    ((ushort4*)yh)[i] = h;
    ((ushort4*)yl)[i] = l;
}

// ---------------------------------------------------------------------------
// Merged weight transpose/convert: z=0: wq->split, z=1: wk->split,
// z=2: wv->single, z=3: wo->single. W[k][n] fp32 -> Wt[n][k] bf16.
// ---------------------------------------------------------------------------
__global__ __launch_bounds__(256) void tconv_all(const float* __restrict__ wq,
                                                 const float* __restrict__ wk,
                                                 const float* __restrict__ wv,
                                                 const float* __restrict__ wo,
                                                 unsigned short* __restrict__ wqth,
                                                 unsigned short* __restrict__ wqtl,
                                                 unsigned short* __restrict__ wkth,
                                                 unsigned short* __restrict__ wktl,
                                                 unsigned short* __restrict__ wvt,
                                                 unsigned short* __restrict__ wot)
{
    __shared__ float T[64][65];
    const int z = blockIdx.z;
    const float* W = (z == 0) ? wq : (z == 1) ? wk : (z == 2) ? wv : wo;
    int n0 = blockIdx.x * 64, k0 = blockIdx.y * 64;
    int tid = threadIdx.x;
    int rr = tid >> 4, cc = (tid & 15) * 4;
#pragma unroll
    for (int p = 0; p < 4; ++p) {
        int r = rr + p * 16;
        float4 x = *(const float4*)&W[(size_t)(k0 + r) * HIDd + n0 + cc];
        T[r][cc] = x.x; T[r][cc + 1] = x.y; T[r][cc + 2] = x.z; T[r][cc + 3] = x.w;
    }
    __syncthreads();
    if (z < 2) {
        unsigned short* Wth = z ? wkth : wqth;
        unsigned short* Wtl = z ? wktl : wqtl;
#pragma unroll
        for (int p = 0; p < 4; ++p) {
            int rn = rr + p * 16;
            float v0 = T[cc][rn], v1 = T[cc + 1][rn], v2 = T[cc + 2][rn], v3 = T[cc + 3][rn];
            ushort4 h, l;
            h.x = f2b(v0); l.x = f2b(v0 - b2f(h.x));
            h.y = f2b(v1); l.y = f2b(v1 - b2f(h.y));
            h.z = f2b(v2); l.z = f2b(v2 - b2f(h.z));
            h.w = f2b(v3); l.w = f2b(v3 - b2f(h.w));
            *(ushort4*)&Wth[(size_t)(n0 + rn) * HIDd + k0 + cc] = h;
            *(ushort4*)&Wtl[(size_t)(n0 + rn) * HIDd + k0 + cc] = l;
        }
    } else {
        unsigned short* Wt = (z == 2) ? wvt : wot;
#pragma unroll
        for (int p = 0; p < 4; ++p) {
            int rn = rr + p * 16;
            ushort4 o;
            o.x = f2b(T[cc][rn]);     o.y = f2b(T[cc + 1][rn]);
            o.z = f2b(T[cc + 2][rn]); o.w = f2b(T[cc + 3][rn]);
            *(ushort4*)&Wt[(size_t)(n0 + rn) * HIDd + k0 + cc] = o;
        }
    }
}

// ---------------------------------------------------------------------------
// Merged q/k/v projection GEMM. Grid (48,16): region = blockIdx.x>>4
// (0=q split, 1=k split, 2=v single); 768 blocks -> 3 blocks/CU so staging
// latency is hidden by co-resident waves (vs 1 block/CU as 3 kernels).
// Per-block math identical to the previous gemm_split / gemm_bf16t MODE1.
// ---------------------------------------------------------------------------
__global__ __launch_bounds__(256) void gemm_qkv(const unsigned short* __restrict__ hsh,
                                                const unsigned short* __restrict__ hsl,
                                                const unsigned short* __restrict__ wqth,
                                                const unsigned short* __restrict__ wqtl,
                                                const unsigned short* __restrict__ wkth,
                                                const unsigned short* __restrict__ wktl,
                                                const unsigned short* __restrict__ wvt,
                                                float* __restrict__ qf,
                                                float* __restrict__ kf,
                                                float* __restrict__ vf)
{
    __shared__ unsigned short AsH[128 * 32], AsL[128 * 32];
    __shared__ unsigned short BsH[128 * 32], BsL[128 * 32];
    const int tid = threadIdx.x;
    const int region = blockIdx.x >> 4;              // 0=q, 1=k, 2=v
    const int bn = (blockIdx.x & 15) * 128;
    const int bm = blockIdx.y * 128;
    const int K = HIDd;
    const int lane = tid & 63, wid = tid >> 6;
    const int wr = (wid >> 1) * 64, wc = (wid & 1) * 64;
    const int lm = lane & 15, lk = (lane >> 4) * 8;
    const int lr = (lane >> 4) * 4;

    f32x4 acc[4][4];
#pragma unroll
    for (int mi = 0; mi < 4; ++mi)
#pragma unroll
        for (int ni = 0; ni < 4; ++ni) acc[mi][ni] = 0.0f;

    if (region < 2) {
        const unsigned short* Bh = region ? wkth : wqth;
        const unsigned short* Bl = region ? wktl : wqtl;
        float* C = region ? kf : qf;
        for (int k0 = 0; k0 < K; k0 += 32) {
#pragma unroll
            for (int l = 0; l < 2; ++l) {
                int L = tid + l * 256;
                int row = L >> 2, c8 = (L & 3) * 8;
                size_t ga = (size_t)(bm + row) * K + k0 + c8;
                size_t gb = (size_t)(bn + row) * K + k0 + c8;
                gload16(&hsh[ga], &AsH[L * 8]);
                gload16(&hsl[ga], &AsL[L * 8]);
                gload16(&Bh[gb], &BsH[L * 8]);
                gload16(&Bl[gb], &BsL[L * 8]);
            }
            __syncthreads();
            short8 ah[4], al[4], bh[4], bl[4];
#pragma unroll
            for (int mi = 0; mi < 4; ++mi) {
                ah[mi] = *(short8*)&AsH[(wr + mi * 16 + lm) * 32 + lk];
                al[mi] = *(short8*)&AsL[(wr + mi * 16 + lm) * 32 + lk];
            }
#pragma unroll
            for (int ni = 0; ni < 4; ++ni) {
                bh[ni] = *(short8*)&BsH[(wc + ni * 16 + lm) * 32 + lk];
                bl[ni] = *(short8*)&BsL[(wc + ni * 16 + lm) * 32 + lk];
            }
#pragma unroll
            for (int mi = 0; mi < 4; ++mi)
#pragma unroll
                for (int ni = 0; ni < 4; ++ni) {
                    acc[mi][ni] = __builtin_amdgcn_mfma_f32_16x16x32_bf16(ah[mi], bh[ni], acc[mi][ni], 0, 0, 0);
                    acc[mi][ni] = __builtin_amdgcn_mfma_f32_16x16x32_bf16(ah[mi], bl[ni], acc[mi][ni], 0, 0, 0);
                    acc[mi][ni] = __builtin_amdgcn_mfma_f32_16x16x32_bf16(al[mi], bh[ni], acc[mi][ni], 0, 0, 0);
                }
            __syncthreads();
        }
#pragma unroll
        for (int mi = 0; mi < 4; ++mi)
#pragma unroll
            for (int ni = 0; ni < 4; ++ni)
#pragma unroll
                for (int r = 0; r < 4; ++r) {
                    int m = bm + wr + mi * 16 + lr + r;
                    int n = bn + wc + ni * 16 + lm;
                    int b_ = m / Ss, s_ = m % Ss;
                    int h_ = n / HDd, d_ = n % HDd;
                    C[(size_t)((b_ * NHh + h_) * Ss + s_) * HDd + d_] = acc[mi][ni][r];
                }
    } else {
        for (int k0 = 0; k0 < K; k0 += 32) {
#pragma unroll
            for (int l = 0; l < 2; ++l) {
                int L = tid + l * 256;
                int row = L >> 2, c8 = (L & 3) * 8;
                gload16(&hsh[(size_t)(bm + row) * K + k0 + c8], &AsH[L * 8]);
                gload16(&wvt[(size_t)(bn + row) * K + k0 + c8], &BsH[L * 8]);
            }
            __syncthreads();
            short8 af[4], bf[4];
#pragma unroll
            for (int mi = 0; mi < 4; ++mi) af[mi] = *(short8*)&AsH[(wr + mi * 16 + lm) * 32 + lk];
#pragma unroll
            for (int ni = 0; ni < 4; ++ni) bf[ni] = *(short8*)&BsH[(wc + ni * 16 + lm) * 32 + lk];
#pragma unroll
            for (int mi = 0; mi < 4; ++mi)
#pragma unroll
                for (int ni = 0; ni < 4; ++ni)
                    acc[mi][ni] = __builtin_amdgcn_mfma_f32_16x16x32_bf16(af[mi], bf[ni], acc[mi][ni], 0, 0, 0);
            __syncthreads();
        }
#pragma unroll
        for (int mi = 0; mi < 4; ++mi)
#pragma unroll
            for (int ni = 0; ni < 4; ++ni)
#pragma unroll
                for (int r = 0; r < 4; ++r) {
                    int m = bm + wr + mi * 16 + lr + r;
                    int n = bn + wc + ni * 16 + lm;
                    int b_ = m / Ss, s_ = m % Ss;
                    int h_ = n / HDd, d_ = n % HDd;
                    vf[(size_t)((b_ * NHh + h_) * Ss + s_) * HDd + d_] = acc[mi][ni][r];
                }
    }
}

// ---------------------------------------------------------------------------
// Single-bf16 MFMA GEMM (wo): C = A @ Bt^T, plain [m][n] output.
// ---------------------------------------------------------------------------
__global__ __launch_bounds__(256) void gemm_bf16t(const unsigned short* __restrict__ A,
                                                  const unsigned short* __restrict__ Bt,
                                                  float* __restrict__ C,
                                                  int M, int N, int K)
{
    __shared__ unsigned short As[128 * 32];
    __shared__ unsigned short Bs[128 * 32];
    const int tid = threadIdx.x;
    const int bm = blockIdx.y * 128, bn = blockIdx.x * 128;
    const int lane = tid & 63, wid = tid >> 6;
    const int wr = (wid >> 1) * 64, wc = (wid & 1) * 64;
    const int lm = lane & 15, lk = (lane >> 4) * 8;

    f32x4 acc[4][4];
#pragma unroll
    for (int mi = 0; mi < 4; ++mi)
#pragma unroll
        for (int ni = 0; ni < 4; ++ni) acc[mi][ni] = 0.0f;

    for (int k0 = 0; k0 < K; k0 += 32) {
#pragma unroll
        for (int l = 0; l < 2; ++l) {
            int L = tid + l * 256;
            int row = L >> 2, c8 = (L & 3) * 8;
            gload16(&A[(size_t)(bm + row) * K + k0 + c8], &As[L * 8]);
            gload16(&Bt[(size_t)(bn + row) * K + k0 + c8], &Bs[L * 8]);
        }
        __syncthreads();
        short8 af[4], bf[4];
#pragma unroll
        for (int mi = 0; mi < 4; ++mi) af[mi] = *(short8*)&As[(wr + mi * 16 + lm) * 32 + lk];
#pragma unroll
        for (int ni = 0; ni < 4; ++ni) bf[ni] = *(short8*)&Bs[(wc + ni * 16 + lm) * 32 + lk];
#pragma unroll
        for (int mi = 0; mi < 4; ++mi)
#pragma unroll
            for (int ni = 0; ni < 4; ++ni)
                acc[mi][ni] = __builtin_amdgcn_mfma_f32_16x16x32_bf16(af[mi], bf[ni], acc[mi][ni], 0, 0, 0);
        __syncthreads();
    }
    const int lr = (lane >> 4) * 4;  // C/D: col=lane&15, row=(lane>>4)*4+reg
#pragma unroll
    for (int mi = 0; mi < 4; ++mi)
#pragma unroll
        for (int ni = 0; ni < 4; ++ni)
#pragma unroll
            for (int r = 0; r < 4; ++r) {
                int m = bm + wr + mi * 16 + lr + r;
                int n = bn + wc + ni * 16 + lm;
                C[(size_t)m * N + n] = acc[mi][ni][r];
            }
}

// ---------------------------------------------------------------------------
// RoPE (fp32 math) -> split bf16 q,k (hi/lo).
// ---------------------------------------------------------------------------
__global__ __launch_bounds__(64) void rope_qk_split(const float* __restrict__ q,
                                                    const float* __restrict__ k,
                                                    unsigned short* __restrict__ qh,
                                                    unsigned short* __restrict__ ql,
                                                    unsigned short* __restrict__ kh,
                                                    unsigned short* __restrict__ kl)
{
    int idx = blockIdx.x;          // bh*S + s
    int s = idx % Ss;
    int d = threadIdx.x;           // 0..63
    float inv = powf(10000.0f, -2.0f * (float)d / 128.0f);
    float fr = (float)s * inv;
    float c = cosf(fr), sn = sinf(fr);
    size_t base = (size_t)idx * HDd;
    float q1 = q[base + d], q2 = q[base + d + 64];
    float k1 = k[base + d], k2 = k[base + d + 64];
    float qa = q1 * c - q2 * sn, qbv = q2 * c + q1 * sn;
    float ka = k1 * c - k2 * sn, kbv = k2 * c + k1 * sn;
    unsigned short h;
    h = f2b(qa);  qh[base + d]      = h; ql[base + d]      = f2b(qa  - b2f(h));
    h = f2b(qbv); qh[base + d + 64] = h; ql[base + d + 64] = f2b(qbv - b2f(h));
    h = f2b(ka);  kh[base + d]      = h; kl[base + d]      = f2b(ka  - b2f(h));
    h = f2b(kbv); kh[base + d + 64] = h; kl[base + d + 64] = f2b(kbv - b2f(h));
}

// ---------------------------------------------------------------------------
// attn = q k^T / sqrt(HD) via split-bf16 MFMA, causal mask to MASKVAL.
// Fully-above-diagonal blocks write NOTHING (softmax skips those loads).
// ---------------------------------------------------------------------------
__global__ __launch_bounds__(256) void attn_qk_split(const unsigned short* __restrict__ qh,
                                                     const unsigned short* __restrict__ ql,
                                                     const unsigned short* __restrict__ kh,
                                                     const unsigned short* __restrict__ kl,
                                                     float* __restrict__ attn)
{
    const int bh = blockIdx.z;
    const int bm = blockIdx.y * 128, bn = blockIdx.x * 128;
    float* C = attn + (size_t)bh * Ss * Ss;
    const int tid = threadIdx.x;

    if (blockIdx.x > blockIdx.y) return;  // fully above diagonal: never read

    const size_t hb = (size_t)bh * Ss * HDd;
    const unsigned short* Ah = qh + hb;
    const unsigned short* Al = ql + hb;
    const unsigned short* Bh = kh + hb;
    const unsigned short* Bl = kl + hb;

    __shared__ unsigned short AsH[128 * 32], AsL[128 * 32];
    __shared__ unsigned short BsH[128 * 32], BsL[128 * 32];
    const int lane = tid & 63, wid = tid >> 6;
    const int wr = (wid >> 1) * 64, wc = (wid & 1) * 64;
    const int lm = lane & 15, lk = (lane >> 4) * 8;

    f32x4 acc[4][4];
#pragma unroll
    for (int mi = 0; mi < 4; ++mi)
#pragma unroll
        for (int ni = 0; ni < 4; ++ni) acc[mi][ni] = 0.0f;

    for (int k0 = 0; k0 < HDd; k0 += 32) {
#pragma unroll
        for (int l = 0; l < 2; ++l) {
            int L = tid + l * 256;
            int row = L >> 2, c8 = (L & 3) * 8;
            size_t ga = (size_t)(bm + row) * HDd + k0 + c8;
            size_t gb = (size_t)(bn + row) * HDd + k0 + c8;
            gload16(&Ah[ga], &AsH[L * 8]);
            gload16(&Al[ga], &AsL[L * 8]);
            gload16(&Bh[gb], &BsH[L * 8]);
            gload16(&Bl[gb], &BsL[L * 8]);
        }
        __syncthreads();
        short8 ah[4], al[4], bh2[4], bl2[4];
#pragma unroll
        for (int mi = 0; mi < 4; ++mi) {
            ah[mi] = *(short8*)&AsH[(wr + mi * 16 + lm) * 32 + lk];
            al[mi] = *(short8*)&AsL[(wr + mi * 16 + lm) * 32 + lk];
        }
#pragma unroll
        for (int ni = 0; ni < 4; ++ni) {
            bh2[ni] = *(short8*)&BsH[(wc + ni * 16 + lm) * 32 + lk];
            bl2[ni] = *(short8*)&BsL[(wc + ni * 16 + lm) * 32 + lk];
        }
#pragma unroll
        for (int mi = 0; mi < 4; ++mi)
#pragma unroll
            for (int ni = 0; ni < 4; ++ni) {
                acc[mi][ni] = __builtin_amdgcn_mfma_f32_16x16x32_bf16(ah[mi], bh2[ni], acc[mi][ni], 0, 0, 0);
                acc[mi][ni] = __builtin_amdgcn_mfma_f32_16x16x32_bf16(ah[mi], bl2[ni], acc[mi][ni], 0, 0, 0);
                acc[mi][ni] = __builtin_amdgcn_mfma_f32_16x16x32_bf16(al[mi], bh2[ni], acc[mi][ni], 0, 0, 0);
            }
        __syncthreads();
    }
    const float scale = 0.08838834764831845f;  // 1/sqrt(128)
    const int lr = (lane >> 4) * 4;
#pragma unroll
    for (int mi = 0; mi < 4; ++mi)
#pragma unroll
        for (int ni = 0; ni < 4; ++ni)
#pragma unroll
            for (int r = 0; r < 4; ++r) {
                int sq = bm + wr + mi * 16 + lr + r;
                int sk = bn + wc + ni * 16 + lm;
                C[(size_t)sq * Ss + sk] = (sk <= sq) ? acc[mi][ni][r] * scale : MASKVAL;
            }
}

// ---------------------------------------------------------------------------
// Row softmax IN PLACE with causal load-skip: lanes whose 4 cols all exceed
// the row index contribute m=MASKVAL, e=0 (bit-identical to reading the
// MASKVAL fill) and write zeros. Loaded float4s never straddle into the
// unwritten above-diagonal region (row+1 is 4-aligned at 128-block edges;
// in-block cols>row hold MASKVAL from the diagonal block).
// ---------------------------------------------------------------------------
__global__ __launch_bounds__(256) void softmax_rows(float* __restrict__ attn)
{
    int row = blockIdx.x;
    int r = row & (Ss - 1);
    float4* a4 = (float4*)(attn + (size_t)row * Ss);
    int tid = threadIdx.x;
    bool act = (tid * 4 <= r);
    float4 x = make_float4(MASKVAL, MASKVAL, MASKVAL, MASKVAL);
    if (act) x = a4[tid];
    float m = fmaxf(fmaxf(x.x, x.y), fmaxf(x.z, x.w));
#pragma unroll
    for (int off = 32; off; off >>= 1) m = fmaxf(m, __shfl_xor(m, off));
    __shared__ float red[4];
    if ((tid & 63) == 0) red[tid >> 6] = m;
    __syncthreads();
    float mm = fmaxf(fmaxf(red[0], red[1]), fmaxf(red[2], red[3]));
    float e0 = expf(x.x - mm), e1 = expf(x.y - mm);
    float e2 = expf(x.z - mm), e3 = expf(x.w - mm);
    float s = e0 + e1 + e2 + e3;
#pragma unroll
    for (int off = 32; off; off >>= 1) s += __shfl_xor(s, off);
    __shared__ float red2[4];
    if ((tid & 63) == 0) red2[tid >> 6] = s;
    __syncthreads();
    float inv = 1.0f / (red2[0] + red2[1] + red2[2] + red2[3]);
    a4[tid] = make_float4(e0 * inv, e1 * inv, e2 * inv, e3 * inv);
}

// ---------------------------------------------------------------------------
// DPP cross-lane helpers (VALU-latency, no LDS pipe).
// ---------------------------------------------------------------------------
template<int CTRL>
__device__ __forceinline__ int dpp_i(int x) {
    return __builtin_amdgcn_update_dpp(0, x, CTRL, 0xF, 0xF, true);
}
__device__ __forceinline__ float wave_sum64(float x) {
    x += __int_as_float(dpp_i<0xB1>(__float_as_int(x)));
    x += __int_as_float(dpp_i<0x4E>(__float_as_int(x)));
    x += __int_as_float(dpp_i<0x141>(__float_as_int(x)));
    x += __int_as_float(dpp_i<0x140>(__float_as_int(x)));
    int xi = __float_as_int(x);
    float a = __int_as_float(__builtin_amdgcn_readlane(xi, 0));
    float b = __int_as_float(__builtin_amdgcn_readlane(xi, 16));
    float c = __int_as_float(__builtin_amdgcn_readlane(xi, 32));
    float d = __int_as_float(__builtin_amdgcn_readlane(xi, 48));
    return (a + c) + (b + d);
}

// 64-bit packed-key (value<<32 | index) helpers: lexicographic min == exact
// float-min with first-index tie-break (values are non-negative floats).
__device__ __forceinline__ unsigned long long u64min(unsigned long long a, unsigned long long b) {
    return a < b ? a : b;
}
template<int CTRL>
__device__ __forceinline__ unsigned long long dpp64(unsigned long long x) {
    int lo = (int)(unsigned)x;
    int hi = (int)(unsigned)(x >> 32);
    unsigned l2 = (unsigned)dpp_i<CTRL>(lo);
    unsigned h2 = (unsigned)dpp_i<CTRL>(hi);
    return ((unsigned long long)h2 << 32) | (unsigned long long)l2;
}
__device__ __forceinline__ unsigned long long wave_min64k(unsigned long long x) {
    x = u64min(x, dpp64<0xB1>(x));
    x = u64min(x, dpp64<0x4E>(x));
    x = u64min(x, dpp64<0x141>(x));
    x = u64min(x, dpp64<0x140>(x));
    int lo = (int)(unsigned)x;
    int hi = (int)(unsigned)(x >> 32);
    unsigned long long a = ((unsigned long long)(unsigned)__builtin_amdgcn_readlane(hi, 0)  << 32) |
                           (unsigned long long)(unsigned)__builtin_amdgcn_readlane(lo, 0);
    unsigned long long b = ((unsigned long long)(unsigned)__builtin_amdgcn_readlane(hi, 16) << 32) |
                           (unsigned long long)(unsigned)__builtin_amdgcn_readlane(lo, 16);
    unsigned long long c = ((unsigned long long)(unsigned)__builtin_amdgcn_readlane(hi, 32) << 32) |
                           (unsigned long long)(unsigned)__builtin_amdgcn_readlane(lo, 32);
    unsigned long long d = ((unsigned long long)(unsigned)__builtin_amdgcn_readlane(hi, 48) << 32) |
                           (unsigned long long)(unsigned)__builtin_amdgcn_readlane(lo, 48);
    return u64min(u64min(a, b), u64min(c, d));
}

__device__ __forceinline__ float f4c(float4 v, int i) {
    return i == 0 ? v.x : (i == 1 ? v.y : (i == 2 ? v.z : v.w));
}

// ---------------------------------------------------------------------------
// A2S sequential scan v5 (proven 390 us): single wave, branchless, causal
// chunk gating via template NC phases, float mf mask, packed u64 argmin.
// (Reverted byte-exact from R1; R2/R3/R4 structural variants all regressed.)
// ---------------------------------------------------------------------------
template<int NC, int NCL>
__device__ __forceinline__ void scan_step(int t, int lane,
                                          const float4* __restrict__ A4,
                                          unsigned char* __restrict__ KP,
                                          float4 (&rb)[4],
                                          float (&sel)[4][4],
                                          float (&mf)[4][4])
{
    const float INFv = __int_as_float(0x7f800000);
    // snapshot row t
    float4 a[NC];
#pragma unroll
    for (int jj = 0; jj < NC; ++jj) a[jj] = rb[jj];
    // prefetch row t+4 (clamped), NCL chunks (one lookahead chunk past NC)
    int tp = t + 4; if (tp > Ss - 1) tp = Ss - 1;
#pragma unroll
    for (int jj = 0; jj < NCL; ++jj) rb[jj] = A4[tp * 256 + jj * 64 + lane];

    // masked row sum — identical add order to v4 (skipped chunks added 0.0)
    float lsum = 0.0f;
#pragma unroll
    for (int jj = 0; jj < NC; ++jj) {
        float c0 = a[jj].x * mf[jj][0], c1 = a[jj].y * mf[jj][1];
        float c2 = a[jj].z * mf[jj][2], c3 = a[jj].w * mf[jj][3];
        lsum += (c0 + c1) + (c2 + c3);
    }
    float tot = wave_sum64(lsum);
    float inv = 1.0f / tot;

    const int local = t - RBc;
    const int base = lane * 4;
    const bool ge = (base >= SBc);   // SBc%4==0 -> i-independent

    // sel update + windowed argmin via packed (value,index) keys
    unsigned long long kmin = 0xFFFFFFFFFFFFFFFFull;
#pragma unroll
    for (int jj = 0; jj < NC; ++jj) {
        unsigned long long kk[4];
#pragma unroll
        for (int i = 0; i < 4; ++i) {
            float sv = fmaf(FFf, sel[jj][i], f4c(a[jj], i) * inv);
            sel[jj][i] = sv;
            int s = jj * 256 + base + i;
            bool win = (s <= local) && (jj > 0 || ge);
            unsigned hi = win ? __float_as_uint(sv) : 0x7f800000u;
            kk[i] = ((unsigned long long)hi << 32) | (unsigned long long)(unsigned)s;
        }
        unsigned long long cm = u64min(u64min(kk[0], kk[1]), u64min(kk[2], kk[3]));
        kmin = u64min(kmin, cm);
    }
    kmin = wave_min64k(kmin);
    const int besti = (int)(unsigned)(kmin & 0xFFFFFFFFull);

    // evict + mask update
#pragma unroll
    for (int jj = 0; jj < NC; ++jj)
#pragma unroll
        for (int i = 0; i < 4; ++i) {
            int s = jj * 256 + base + i;
            bool e = (s == besti);
            sel[jj][i] = e ? INFv : sel[jj][i];
            mf[jj][i]  = e ? 0.0f : mf[jj][i];
        }

    // keep row t+1 (chunks 0..NC-1; scores are exactly 0 above, don't-care)
    uchar4* kp4 = (uchar4*)(KP + (size_t)(t + 1) * Ss);
#pragma unroll
    for (int jj = 0; jj < NC; ++jj) {
        uchar4 kb;
        kb.x = (unsigned char)mf[jj][0];
        kb.y = (unsigned char)mf[jj][1];
        kb.z = (unsigned char)mf[jj][2];
        kb.w = (unsigned char)mf[jj][3];
        kp4[jj * 64 + lane] = kb;
    }
}

__global__ __launch_bounds__(64) void scan_kernel5(const float* __restrict__ scores,
                                                   unsigned char* __restrict__ keep)
{
    int bh = blockIdx.x;
    int lane = threadIdx.x;
    const float4* A4 = (const float4*)(scores + (size_t)bh * Ss * Ss);
    unsigned char* KP = keep + (size_t)bh * Ss * Ss;

    float sel[4][4];
    float mf[4][4];
#pragma unroll
    for (int jj = 0; jj < 4; ++jj)
#pragma unroll
        for (int i = 0; i < 4; ++i) { sel[jj][i] = 0.0f; mf[jj][i] = 1.0f; }

    // ---- warmup rows 0..162: chunk 0 only (rows <163 are zero beyond col 162) ----
    float4 w0 = A4[0 * 256 + lane];
    float4 w1 = A4[1 * 256 + lane];
    float4 w2 = A4[2 * 256 + lane];
    float4 w3 = A4[3 * 256 + lane];
#define WSTEP(W, NEXT)                                                       \
    do {                                                                     \
        float4 _a = W;                                                       \
        W = A4[(NEXT) * 256 + lane];                                         \
        sel[0][0] = fmaf(FFf, sel[0][0], _a.x);                              \
        sel[0][1] = fmaf(FFf, sel[0][1], _a.y);                              \
        sel[0][2] = fmaf(FFf, sel[0][2], _a.z);                              \
        sel[0][3] = fmaf(FFf, sel[0][3], _a.w);                              \
    } while (0)
    for (int r = 0; r < 160; r += 4) {
        WSTEP(w0, r + 4); WSTEP(w1, r + 5); WSTEP(w2, r + 6); WSTEP(w3, r + 7);
    }
#undef WSTEP
    {   // rows 160..162 tail (w3 = row 163 discarded)
        float4 tl[3] = { w0, w1, w2 };
#pragma unroll
        for (int u = 0; u < 3; ++u) {
            sel[0][0] = fmaf(FFf, sel[0][0], tl[u].x);
            sel[0][1] = fmaf(FFf, sel[0][1], tl[u].y);
            sel[0][2] = fmaf(FFf, sel[0][2], tl[u].z);
            sel[0][3] = fmaf(FFf, sel[0][3], tl[u].w);
        }
    }

    // ---- init scan prefetch: rows 163..166, chunk 0 ----
    float4 rb[4][4];
#pragma unroll
    for (int slot = 0; slot < 4; ++slot)
        rb[slot][0] = A4[(163 + slot) * 256 + lane];

    // ---- phased scan: t = 163..1022 (keep rows 164..1023) ----
    for (int t0 = 163; t0 < 255; t0 += 4) {           // 92 steps, NC=1
        scan_step<1, 2>(t0 + 0, lane, A4, KP, rb[0], sel, mf);
        scan_step<1, 2>(t0 + 1, lane, A4, KP, rb[1], sel, mf);
        scan_step<1, 2>(t0 + 2, lane, A4, KP, rb[2], sel, mf);
        scan_step<1, 2>(t0 + 3, lane, A4, KP, rb[3], sel, mf);
    }
    for (int t0 = 255; t0 < 511; t0 += 4) {           // 256 steps, NC=2
        scan_step<2, 3>(t0 + 0, lane, A4, KP, rb[0], sel, mf);
        scan_step<2, 3>(t0 + 1, lane, A4, KP, rb[1], sel, mf);
        scan_step<2, 3>(t0 + 2, lane, A4, KP, rb[2], sel, mf);
        scan_step<2, 3>(t0 + 3, lane, A4, KP, rb[3], sel, mf);
    }
    for (int t0 = 511; t0 < 767; t0 += 4) {           // 256 steps, NC=3
        scan_step<3, 4>(t0 + 0, lane, A4, KP, rb[0], sel, mf);
        scan_step<3, 4>(t0 + 1, lane, A4, KP, rb[1], sel, mf);
        scan_step<3, 4>(t0 + 2, lane, A4, KP, rb[2], sel, mf);
        scan_step<3, 4>(t0 + 3, lane, A4, KP, rb[3], sel, mf);
    }
    for (int t0 = 767; t0 < 1023; t0 += 4) {          // 256 steps, NC=4
        scan_step<4, 4>(t0 + 0, lane, A4, KP, rb[0], sel, mf);
        scan_step<4, 4>(t0 + 1, lane, A4, KP, rb[1], sel, mf);
        scan_step<4, 4>(t0 + 2, lane, A4, KP, rb[2], sel, mf);
        scan_step<4, 4>(t0 + 3, lane, A4, KP, rb[3], sel, mf);
    }
}

// ---------------------------------------------------------------------------
// Fused mask + renorm + PV: ctx = (keep.*P) @ V / rowsum(keep.*P).
// ---------------------------------------------------------------------------
__global__ __launch_bounds__(256) void pv_renorm(const float* __restrict__ scores,
                                                 const unsigned char* __restrict__ keep,
                                                 const float* __restrict__ v,
                                                 unsigned short* __restrict__ ctxb)
{
    int bh = blockIdx.z;
    int b_ = bh / NHh, h_ = bh % NHh;
    const float* P = scores + (size_t)bh * Ss * Ss;
    const unsigned char* KPm = keep + (size_t)bh * Ss * Ss;
    const float* V = v + (size_t)bh * Ss * HDd;
    int bm = blockIdx.y * 64, bn = blockIdx.x * 64;
    int tid = threadIdx.x, tx = tid & 15, ty = tid >> 4;
    __shared__ float As[16][65];
    __shared__ float Bs[16][64];
    float acc[4][4] = {};
    float rs[4] = {};
    int kend = bm + 64;  // causal truncation (covers full causal row extent)
    for (int k0 = 0; k0 < kend; k0 += 16) {
#pragma unroll
        for (int l = 0; l < 4; ++l) {
            int idx = tid + l * 256;
            int r = idx >> 4, c = idx & 15;
            int row = bm + r;
            float p = P[(size_t)row * Ss + k0 + c];
            if (row > CBc && !KPm[(size_t)row * Ss + k0 + c]) p = 0.0f;
            As[c][r] = p;
        }
#pragma unroll
        for (int l = 0; l < 4; ++l) {
            int idx = tid + l * 256;
            int r = idx >> 6, c = idx & 63;
            Bs[r][c] = V[(size_t)(k0 + r) * HDd + bn + c];
        }
        __syncthreads();
#pragma unroll
        for (int kk = 0; kk < 16; ++kk) {
            float a[4], b[4];
#pragma unroll
            for (int i = 0; i < 4; ++i) a[i] = As[kk][ty * 4 + i];
#pragma unroll
            for (int j = 0; j < 4; ++j) b[j] = Bs[kk][tx * 4 + j];
#pragma unroll
            for (int i = 0; i < 4; ++i) rs[i] += a[i];
#pragma unroll
            for (int i = 0; i < 4; ++i)
#pragma unroll
                for (int j = 0; j < 4; ++j)
                    acc[i][j] = fmaf(a[i], b[j], acc[i][j]);
        }
        __syncthreads();
    }
#pragma unroll
    for (int i = 0; i < 4; ++i) {
        float inv = 1.0f / rs[i];   // rs > 0 (diagonal prob always kept)
        int sq = bm + ty * 4 + i;
#pragma unroll
        for (int j = 0; j < 4; ++j) {
            int d = bn + tx * 4 + j;
            ctxb[(size_t)(b_ * Ss + sq) * HIDd + h_ * HDd + d] = f2b(acc[i][j] * inv);
        }
    }
}

// ---------------------------------------------------------------------------
extern "C" void kernel_launch(void* const* d_in, const int* in_sizes, int n_in,
                              void* d_out, int out_size, void* d_ws, size_t ws_size,
                              hipStream_t stream)
{
    const float* hs = (const float*)d_in[0];
    const float* wq = (const float*)d_in[1];
    const float* wk = (const float*)d_in[2];
    const float* wv = (const float*)d_in[3];
    const float* wo = (const float*)d_in[4];
    float* out = (float*)d_out;

    float* ws = (float*)d_ws;
    size_t off = 0;
    float* qf   = ws + off; off += (size_t)NBH * Ss * HDd;   // 16 MB (reused: ctxb)
    float* kf   = ws + off; off += (size_t)NBH * Ss * HDd;   // 16 MB
    float* vf   = ws + off; off += (size_t)NBH * Ss * HDd;   // 16 MB
    float* attn = ws + off; off += (size_t)NBH * Ss * Ss;    // 128 MB
    unsigned char* keep = (unsigned char*)(ws + off); off += (size_t)NBH * Ss * Ss / 4; // 32 MB
    unsigned short* wot = (unsigned short*)(ws + off); off += (size_t)HIDd * HIDd / 2;  // 8 MB

    // Transients overlaid on attn (dead before attn is written). 8 MB = 2M floats each.
    unsigned short* hsh  = (unsigned short*)(attn);
    unsigned short* hsl  = (unsigned short*)(attn + 2u * 1024 * 1024);
    unsigned short* wqth = (unsigned short*)(attn + 4u * 1024 * 1024);
    unsigned short* wqtl = (unsigned short*)(attn + 6u * 1024 * 1024);
    unsigned short* wkth = (unsigned short*)(attn + 8u * 1024 * 1024);
    unsigned short* wktl = (unsigned short*)(attn + 10u * 1024 * 1024);
    unsigned short* wvt  = (unsigned short*)(attn + 12u * 1024 * 1024);
    // q/k split bf16 overlaid on keep (keep written only by the scan, later):
    unsigned short* qh = (unsigned short*)keep;
    unsigned short* ql = (unsigned short*)(keep + 8u * 1024 * 1024);
    unsigned short* kh = (unsigned short*)(keep + 16u * 1024 * 1024);
    unsigned short* kl = (unsigned short*)(keep + 24u * 1024 * 1024);
    // ctxb overlays qf (qf dead after rope):
    unsigned short* ctxb = (unsigned short*)qf;

    dim3 blk(256);
    const int M = Bb * Ss;  // 2048

    // hs -> split bf16
    conv_split<<<dim3((M * HIDd / 4 + 255) / 256), blk, 0, stream>>>(hs, hsh, hsl, M * HIDd / 4);

    // all 4 weight transposes in one launch
    tconv_all<<<dim3(HIDd / 64, HIDd / 64, 4), blk, 0, stream>>>(
        wq, wk, wv, wo, wqth, wqtl, wkth, wktl, wvt, wot);

    // merged q/k/v projection (768 blocks -> 3 blocks/CU)
    gemm_qkv<<<dim3(48, M / 128), blk, 0, stream>>>(
        hsh, hsl, wqth, wqtl, wkth, wktl, wvt, qf, kf, vf);

    // RoPE (fp32 math) -> split bf16 q,k
    rope_qk_split<<<dim3(NBH * Ss), dim3(64), 0, stream>>>(qf, kf, qh, ql, kh, kl);

    // QK^T (split-precision MFMA) + causal mask; above-diag blocks skipped
    attn_qk_split<<<dim3(Ss / 128, Ss / 128, NBH), blk, 0, stream>>>(qh, ql, kh, kl, attn);

    // attn -> normalized scores, in place (causal load-skip)
    softmax_rows<<<dim3(NROWS), blk, 0, stream>>>(attn);

    // sequential A2S scan -> keep mask (v5, proven)
    scan_kernel5<<<dim3(NBH), dim3(64), 0, stream>>>(attn, keep);

    // fused mask + renorm + PV (fp32 math, bf16 out)
    pv_renorm<<<dim3(HDd / 64, Ss / 64, NBH), blk, 0, stream>>>(attn, keep, vf, ctxb);

    // out = ctx @ wo (bf16 MFMA, fp32 out)
    gemm_bf16t<<<dim3(HIDd / 128, M / 128), blk, 0, stream>>>(ctxb, wot, out, M, HIDd, HIDd);
}